// Round 6
// baseline (173.489 us; speedup 1.0000x reference)
//
#include <hip/hip_runtime.h>

#define DM 1024
#define NH 16
#define DK 64
#define BB 2
#define SS 2048

typedef unsigned short u16;
typedef unsigned int   u32;
typedef __bf16 bf16x8 __attribute__((ext_vector_type(8)));
typedef float  f32x4  __attribute__((ext_vector_type(4)));

__device__ __forceinline__ u16 f2bf(float f){
  u32 u = __float_as_uint(f);
  u32 r = (u + 0x7FFFu + ((u >> 16) & 1u)) >> 16;   // RNE
  return (u16)r;
}
__device__ __forceinline__ float bf2f(u16 v){ return __uint_as_float(((u32)v) << 16); }

// packed bf16 convert: low16 = bf16(lo), high16 = bf16(hi), RNE
__device__ __forceinline__ u32 cvtpk(float lo, float hi){
  u32 r;
  asm volatile("v_cvt_pk_bf16_f32 %0, %1, %2" : "=v"(r) : "v"(lo), "v"(hi));
  return r;
}

__device__ __forceinline__ void gl16(const void* g, void* l){
  __builtin_amdgcn_global_load_lds((const __attribute__((address_space(1))) u32*)g,
                                   (__attribute__((address_space(3))) u32*)l, 16, 0, 0);
}
__device__ __forceinline__ f32x4 mfma16(bf16x8 a, bf16x8 b, f32x4 c){
  return __builtin_amdgcn_mfma_f32_16x16x32_bf16(a, b, c, 0, 0, 0);
}

// ---------------- merged cast (x + 4 weights), 4 f32/thread ----------------
__global__ void k_cast(const float* __restrict__ x,  const float* __restrict__ wq,
                       const float* __restrict__ wk, const float* __restrict__ wv,
                       const float* __restrict__ wo, u16* __restrict__ xb,
                       u16* __restrict__ wb){
  int e = blockIdx.x*1024 + threadIdx.x*4;
  int r = e >> 20;
  const float* s; u16* d; int local;
  if (r < 4){ s = x; d = xb; local = e; }
  else {
    const float* ws[4] = {wq, wk, wv, wo};
    int w = r - 4;
    local = e & 0xFFFFF;
    s = ws[w]; d = wb + ((size_t)w << 20);
  }
  float4 v = *(const float4*)(s + local);
  uint2 t; t.x = cvtpk(v.x, v.y); t.y = cvtpk(v.z, v.w);
  *(uint2*)(d + local) = t;
}

// ---------------- GEMM core: C[m][n] = sum_k A[m][k]*B[n][k] ----------------
// SWAP=false: acc reg r -> m (A rows), lane&15 -> n (verified R2).
// SWAP=true : operands swapped -> acc reg r -> n, lane&15 -> m (lets the
//             epilogue hold 4 consecutive n per lane for in-register RoPE).
template<bool SWAP>
__device__ __forceinline__ void gemm_core(const u16* __restrict__ A, const u16* __restrict__ Bw,
                                          u16* As, u16* Bs, f32x4 (&acc)[4][4]){
  const int tid = threadIdx.x, lane = tid & 63, wid = tid >> 6;
  const int m0 = blockIdx.y * 128, n0 = blockIdx.x * 128;
  const int wm = (wid >> 1) * 64, wn = (wid & 1) * 64;
  for (int k0 = 0; k0 < DM; k0 += 64){
    __syncthreads();
    #pragma unroll
    for (int i = 0; i < 4; i++){
      int row = i*32 + (tid >> 3);
      int cb  = (tid & 7) * 8;
      gl16(A  + (size_t)(m0+row)*DM + k0 + cb, (char*)As + i*4096 + tid*16);
      gl16(Bw + (size_t)(n0+row)*DM + k0 + cb, (char*)Bs + i*4096 + tid*16);
    }
    __syncthreads();
    #pragma unroll
    for (int kk = 0; kk < 2; kk++){
      const int co = kk*64 + (lane >> 4) * 16;
      bf16x8 af[4], bfr[4];
      #pragma unroll
      for (int mi = 0; mi < 4; mi++)
        af[mi] = *(const bf16x8*)((const char*)As + (wm + mi*16 + (lane & 15))*128 + co);
      #pragma unroll
      for (int ni = 0; ni < 4; ni++)
        bfr[ni] = *(const bf16x8*)((const char*)Bs + (wn + ni*16 + (lane & 15))*128 + co);
      #pragma unroll
      for (int mi = 0; mi < 4; mi++)
        #pragma unroll
        for (int ni = 0; ni < 4; ni++)
          acc[mi][ni] = SWAP ? mfma16(bfr[ni], af[mi], acc[mi][ni])
                             : mfma16(af[mi], bfr[ni], acc[mi][ni]);
    }
  }
}

// QKV GEMM with fused RoPE (applied in fp32 before bf16 pack) for z in {0,1}.
__global__ __launch_bounds__(256) void k_gemm_qkv(const u16* __restrict__ xb, const u16* __restrict__ Wb,
                                                  u16* __restrict__ Qb, u16* __restrict__ Kb,
                                                  u16* __restrict__ Vb, const int* __restrict__ pos){
  __shared__ __align__(16) u16 As[8192];
  __shared__ __align__(16) u16 Bs[8192];
  const int z = blockIdx.z;
  const u16* Bw = Wb + ((size_t)z << 20);
  u16* C = (z == 0) ? Qb : ((z == 1) ? Kb : Vb);
  f32x4 acc[4][4] = {};
  gemm_core<true>(xb, Bw, As, Bs, acc);
  const int lane = threadIdx.x & 63, wid = threadIdx.x >> 6;
  const int m0 = blockIdx.y*128 + (wid >> 1)*64, n0 = blockIdx.x*128 + (wid & 1)*64;
  const int ql = lane & 15, lg = lane >> 4;
  const bool dorope = (z < 2);
  #pragma unroll
  for (int mi = 0; mi < 4; mi++){
    const int mrow = m0 + mi*16 + ql;
    const float pf = (float)pos[mrow & (SS-1)];
    #pragma unroll
    for (int ni = 0; ni < 4; ni++){
      const int nb = n0 + ni*16 + lg*4;        // 4 consecutive n, even-aligned
      float o0 = acc[mi][ni][0], o1 = acc[mi][ni][1];
      float o2 = acc[mi][ni][2], o3 = acc[mi][ni][3];
      if (dorope){
        int j0 = (nb >> 1) & 31;               // pair index within head (nb mult of 4)
        float s, c;
        sincosf(pf * exp2f(-0.4152410118609203f * (float)j0), &s, &c);
        float t0 = o0*c - o1*s, t1 = o0*s + o1*c;
        o0 = t0; o1 = t1;
        sincosf(pf * exp2f(-0.4152410118609203f * (float)(j0+1)), &s, &c);
        t0 = o2*c - o3*s; t1 = o2*s + o3*c;
        o2 = t0; o3 = t1;
      }
      uint2 w; w.x = cvtpk(o0, o1); w.y = cvtpk(o2, o3);
      *(uint2*)(C + (size_t)mrow*DM + nb) = w;
    }
  }
}

__global__ __launch_bounds__(256) void k_gemm_out(const u16* __restrict__ AO, const u16* __restrict__ Wo,
                                                  float* __restrict__ Co){
  __shared__ __align__(16) u16 As[8192];
  __shared__ __align__(16) u16 Bs[8192];
  f32x4 acc[4][4] = {};
  gemm_core<false>(AO, Wo, As, Bs, acc);
  const int lane = threadIdx.x & 63, wid = threadIdx.x >> 6;
  const int m0 = blockIdx.y*128 + (wid >> 1)*64, n0 = blockIdx.x*128 + (wid & 1)*64;
  #pragma unroll
  for (int mi = 0; mi < 4; mi++)
    #pragma unroll
    for (int ni = 0; ni < 4; ni++)
      #pragma unroll
      for (int r = 0; r < 4; r++){
        int m = m0 + mi*16 + (lane >> 4)*4 + r;
        int n = n0 + ni*16 + (lane & 15);
        Co[(size_t)m*DM + n] = acc[mi][ni][r];
      }
}

// ---------------- flash attention, causal, 4 waves x 32 q-rows ----------------
// R6: 256-thread blocks, QBLK=128 kept, but each wave owns TWO 16-row q-streams.
// K-frag and V-frag ds_reads are issued once and feed both streams' MFMAs ->
// per-block-tile b128 reads drop 144 -> ~80 and per-wave MFMA density doubles.
__device__ __forceinline__ void sm_stream(f32x4 (&sf)[4], int kv0, int qbase, int ql, int lg,
                                          float& m, float& lsum, f32x4 (&oacc)[4],
                                          char* Pbuf, int prow){
  const float SC = 0.18033688011112042f;      // (1/sqrt(64)) * log2(e)
  const float THR = 8.0f / SC;
  if (kv0 + 63 > qbase){                      // diagonal overlap: mask
    const int qa = qbase + ql;
    #pragma unroll
    for (int f = 0; f < 4; f++)
      #pragma unroll
      for (int r = 0; r < 4; r++){
        int kva = kv0 + f*16 + lg*4 + r;
        sf[f][r] = (kva <= qa) ? sf[f][r] : -3e38f;
      }
  }
  float mx01 = fmaxf(fmaxf(sf[0][0], sf[0][1]), fmaxf(sf[0][2], sf[0][3]));
  float mx23 = fmaxf(fmaxf(sf[1][0], sf[1][1]), fmaxf(sf[1][2], sf[1][3]));
  float mx45 = fmaxf(fmaxf(sf[2][0], sf[2][1]), fmaxf(sf[2][2], sf[2][3]));
  float mx67 = fmaxf(fmaxf(sf[3][0], sf[3][1]), fmaxf(sf[3][2], sf[3][3]));
  float mx = fmaxf(fmaxf(mx01, mx23), fmaxf(mx45, mx67));
  if (!__all(mx <= m + THR)){                 // defer-max
    mx = fmaxf(mx, __shfl_xor(mx, 16));
    mx = fmaxf(mx, __shfl_xor(mx, 32));
    const float mn = fmaxf(m, mx);
    const float alpha = exp2f((m - mn)*SC);
    #pragma unroll
    for (int ni = 0; ni < 4; ni++) oacc[ni] *= alpha;
    lsum *= alpha;
    m = mn;
  }
  const float nms = -m*SC;
  float p[4][4];
  float psum = 0.f;
  #pragma unroll
  for (int f = 0; f < 4; f++)
    #pragma unroll
    for (int r = 0; r < 4; r++){
      p[f][r] = exp2f(fmaf(sf[f][r], SC, nms));
      psum += p[f][r];
    }
  lsum += psum;
  #pragma unroll
  for (int f = 0; f < 4; f++)
    #pragma unroll
    for (int r = 0; r < 4; r += 2){
      int kv = f*16 + lg*4 + r;
      int byteoff = (prow*128 + kv*2) ^ ((prow & 7) << 4);
      *(u32*)(Pbuf + byteoff) = cvtpk(p[f][r], p[f][r+1]);
    }
}

__global__ __launch_bounds__(256) void k_attn(const u16* __restrict__ Q, const u16* __restrict__ K,
                                              const u16* __restrict__ V, u16* __restrict__ AO){
  __shared__ __align__(16) u16 Ks[2][64*64];
  __shared__ __align__(16) u16 Vt[2][64*64];
  __shared__ __align__(16) u16 Ps[4][32*64];
  const int tid = threadIdx.x, lane = tid & 63, wid = tid >> 6;
  const int b = blockIdx.z, h = blockIdx.y;
  const int qb = b ? (15 - (int)blockIdx.x) : (int)blockIdx.x;   // balanced pairing
  const int qw = qb*128 + wid*32;                                 // wave's 32-row base
  const size_t base = ((size_t)b*SS)*DM + (size_t)h*DK;
  const int ql = lane & 15, lg = lane >> 4;
  const int NT = 2*qb + 2;

  const u16* qpA = Q + base + (size_t)(qw + ql)*DM + lg*8;
  const u16* qpB = qpA + 16*DM;
  bf16x8 qf0A = *(const bf16x8*)(qpA), qf1A = *(const bf16x8*)(qpA + 32);
  bf16x8 qf0B = *(const bf16x8*)(qpB), qf1B = *(const bf16x8*)(qpB + 32);

  f32x4 oaccA[4] = {}, oaccB[4] = {};
  float mA = -3e38f, mB = -3e38f, lsA = 0.f, lsB = 0.f;
  const float SC = 0.18033688011112042f;

  const int kvl = (tid & 31)*2, dbase = (tid >> 5)*8;

  // ---- prologue: stage tile 0 ----
  #pragma unroll
  for (int i = 0; i < 2; i++){
    int L = i*4096 + tid*16;
    int kv = L >> 7;
    int inner = (L & 127) ^ ((kv & 7) << 4);
    gl16(K + base + (size_t)kv*DM + (inner >> 1), (char*)Ks[0] + L);
  }
  {
    const u16* vsrc = V + base + (size_t)kvl*DM + dbase;
    bf16x8 r0 = *(const bf16x8*)(vsrc);
    bf16x8 r1 = *(const bf16x8*)(vsrc + DM);
    const u16* p0 = (const u16*)&r0; const u16* p1 = (const u16*)&r1;
    #pragma unroll
    for (int j = 0; j < 8; j++){
      int d = dbase + j;
      int byteoff = (d*128 + kvl*2) ^ ((d & 7) << 4);
      *(u32*)((char*)Vt[0] + byteoff) = (u32)p0[j] | ((u32)p1[j] << 16);
    }
  }
  __syncthreads();

  int cur = 0;
  for (int kt = 0; kt < NT; kt++){
    const int kv0 = kt*64;
    const bool more = (kt < NT-1);
    bf16x8 vr0, vr1;
    if (more){
      const int kn0 = kv0 + 64;
      #pragma unroll
      for (int i = 0; i < 2; i++){
        int L = i*4096 + tid*16;
        int kv = L >> 7;
        int inner = (L & 127) ^ ((kv & 7) << 4);
        gl16(K + base + (size_t)(kn0+kv)*DM + (inner >> 1), (char*)Ks[cur^1] + L);
      }
      const u16* vsrc = V + base + (size_t)(kn0+kvl)*DM + dbase;
      vr0 = *(const bf16x8*)(vsrc);
      vr1 = *(const bf16x8*)(vsrc + DM);
    }

    if (kv0 <= qw + 31){                        // wave-uniform active gate (both streams)
      // QK^T swapped, K-frags shared across both q-streams
      f32x4 sfA[4] = {}, sfB[4] = {};
      __builtin_amdgcn_s_setprio(1);
      #pragma unroll
      for (int kk = 0; kk < 2; kk++){
        const int co = kk*64 + lg*16;
        #pragma unroll
        for (int f = 0; f < 4; f++){
          int kvr = f*16 + ql;
          bf16x8 kf = *(const bf16x8*)((const char*)Ks[cur] + ((kvr*128 + co) ^ ((kvr & 7) << 4)));
          sfA[f] = mfma16(kf, kk ? qf1A : qf0A, sfA[f]);
          sfB[f] = mfma16(kf, kk ? qf1B : qf0B, sfB[f]);
        }
      }
      __builtin_amdgcn_s_setprio(0);

      sm_stream(sfA, kv0, qw,      ql, lg, mA, lsA, oaccA, (char*)Ps[wid], ql);
      sm_stream(sfB, kv0, qw + 16, ql, lg, mB, lsB, oaccB, (char*)Ps[wid], 16 + ql);

      // PV swapped, V-frags shared across both streams
      __builtin_amdgcn_s_setprio(1);
      #pragma unroll
      for (int kk = 0; kk < 2; kk++){
        bf16x8 pfA = *(const bf16x8*)((const char*)Ps[wid] +
                      ((ql*128 + kk*64 + lg*16) ^ ((ql & 7) << 4)));
        bf16x8 pfB = *(const bf16x8*)((const char*)Ps[wid] +
                      (((16+ql)*128 + kk*64 + lg*16) ^ ((ql & 7) << 4)));
        #pragma unroll
        for (int ni = 0; ni < 4; ni++){
          int d = ni*16 + ql;
          bf16x8 vf = *(const bf16x8*)((const char*)Vt[cur] +
                        ((d*128 + kk*64 + lg*16) ^ ((d & 7) << 4)));
          oaccA[ni] = mfma16(vf, pfA, oaccA[ni]);
          oaccB[ni] = mfma16(vf, pfB, oaccB[ni]);
        }
      }
      __builtin_amdgcn_s_setprio(0);
    }

    if (more){
      const u16* p0 = (const u16*)&vr0; const u16* p1 = (const u16*)&vr1;
      #pragma unroll
      for (int j = 0; j < 8; j++){
        int d = dbase + j;
        int byteoff = (d*128 + kvl*2) ^ ((d & 7) << 4);
        *(u32*)((char*)Vt[cur^1] + byteoff) = (u32)p0[j] | ((u32)p1[j] << 16);
      }
    }
    __syncthreads();
    cur ^= 1;
  }

  // epilogue: per-stream lsum reduce, O^T through LDS, coalesced store of 32 rows
  lsA += __shfl_xor(lsA, 16); lsA += __shfl_xor(lsA, 32);
  lsB += __shfl_xor(lsB, 16); lsB += __shfl_xor(lsB, 32);
  const float rlA = 1.0f / lsA, rlB = 1.0f / lsB;
  #pragma unroll
  for (int ni = 0; ni < 4; ni++)
    #pragma unroll
    for (int r = 0; r < 4; r += 2){
      int d = ni*16 + lg*4 + r;
      int boA = (ql*128 + d*2) ^ ((ql & 7) << 4);
      int boB = (((16+ql)*128) + d*2) ^ ((ql & 7) << 4);
      *(u32*)((char*)Ps[wid] + boA) = cvtpk(oaccA[ni][r]*rlA, oaccA[ni][r+1]*rlA);
      *(u32*)((char*)Ps[wid] + boB) = cvtpk(oaccB[ni][r]*rlB, oaccB[ni][r+1]*rlB);
    }
  #pragma unroll
  for (int pass = 0; pass < 4; pass++){
    int qr = pass*8 + (lane >> 3);
    int d0 = (lane & 7)*8;
    bf16x8 row = *(const bf16x8*)((const char*)Ps[wid] + ((qr*128 + d0*2) ^ ((qr & 7) << 4)));
    *(bf16x8*)(AO + base + (size_t)(qw + qr)*DM + d0) = row;
  }
}

// ---------------- launch ----------------
extern "C" void kernel_launch(void* const* d_in, const int* in_sizes, int n_in,
                              void* d_out, int out_size, void* d_ws, size_t ws_size,
                              hipStream_t stream){
  const float* x   = (const float*)d_in[0];
  const float* Wq  = (const float*)d_in[1];
  const float* Wk  = (const float*)d_in[2];
  const float* Wv  = (const float*)d_in[3];
  const float* Wo  = (const float*)d_in[4];
  const int*   pos = (const int*)d_in[5];
  float* out = (float*)d_out;

  const size_t NEED = (size_t)40 << 20;
  if (ws_size < NEED){
    hipMemsetAsync(d_out, 0x7f, (size_t)out_size * sizeof(float), stream);
    return;
  }

  char* ws = (char*)d_ws;
  u16* xb = (u16*)(ws);
  u16* Wb = (u16*)(ws + ((size_t)8  << 20));
  u16* Qb = (u16*)(ws + ((size_t)16 << 20));
  u16* Kb = (u16*)(ws + ((size_t)24 << 20));
  u16* Vb = (u16*)(ws + ((size_t)32 << 20));
  u16* AO = xb;

  k_cast<<<8192, 256, 0, stream>>>(x, Wq, Wk, Wv, Wo, xb, Wb);
  k_gemm_qkv<<<dim3(8, 32, 3), 256, 0, stream>>>(xb, Wb, Qb, Kb, Vb, pos);
  k_attn<<<dim3(16, 16, 2), 256, 0, stream>>>(Qb, Kb, Vb, AO);
  k_gemm_out<<<dim3(8, 32), 256, 0, stream>>>(AO, Wb + ((size_t)3 << 20), out);
}

// Round 7
// 163.761 us; speedup vs baseline: 1.0594x; 1.0594x over previous
//
#include <hip/hip_runtime.h>

#define DM 1024
#define NH 16
#define DK 64
#define BB 2
#define SS 2048

typedef unsigned short u16;
typedef unsigned int   u32;
typedef __bf16 bf16x8 __attribute__((ext_vector_type(8)));
typedef float  f32x4  __attribute__((ext_vector_type(4)));

__device__ __forceinline__ u16 f2bf(float f){
  u32 u = __float_as_uint(f);
  u32 r = (u + 0x7FFFu + ((u >> 16) & 1u)) >> 16;   // RNE
  return (u16)r;
}
__device__ __forceinline__ float bf2f(u16 v){ return __uint_as_float(((u32)v) << 16); }

// packed bf16 convert: low16 = bf16(lo), high16 = bf16(hi), RNE
__device__ __forceinline__ u32 cvtpk(float lo, float hi){
  u32 r;
  asm volatile("v_cvt_pk_bf16_f32 %0, %1, %2" : "=v"(r) : "v"(lo), "v"(hi));
  return r;
}

__device__ __forceinline__ void gl16(const void* g, void* l){
  __builtin_amdgcn_global_load_lds((const __attribute__((address_space(1))) u32*)g,
                                   (__attribute__((address_space(3))) u32*)l, 16, 0, 0);
}
__device__ __forceinline__ f32x4 mfma16(bf16x8 a, bf16x8 b, f32x4 c){
  return __builtin_amdgcn_mfma_f32_16x16x32_bf16(a, b, c, 0, 0, 0);
}

// ------- merged cast (x + 4 weights) + RoPE trig-table fill (tail blocks) -------
// blocks [0,8192): cast 8M f32 -> bf16. blocks [8192,8448): fill tab[p][j] =
// (cos(p*theta^-(j/32)), sin(...)) for p in [0,2048), j in [0,32)  (512 KB).
__global__ void k_cast(const float* __restrict__ x,  const float* __restrict__ wq,
                       const float* __restrict__ wk, const float* __restrict__ wv,
                       const float* __restrict__ wo, u16* __restrict__ xb,
                       u16* __restrict__ wb, float* __restrict__ tab){
  if (blockIdx.x >= 8192){
    int e = (blockIdx.x - 8192)*256 + threadIdx.x;   // [0, 65536)
    int p = e >> 5, j = e & 31;
    float s, c;
    sincosf((float)p * exp2f(-0.4152410118609203f * (float)j), &s, &c);
    float2 v; v.x = c; v.y = s;
    *(float2*)(tab + e*2) = v;
    return;
  }
  int e = blockIdx.x*1024 + threadIdx.x*4;
  int r = e >> 20;
  const float* s; u16* d; int local;
  if (r < 4){ s = x; d = xb; local = e; }
  else {
    const float* ws[4] = {wq, wk, wv, wo};
    int w = r - 4;
    local = e & 0xFFFFF;
    s = ws[w]; d = wb + ((size_t)w << 20);
  }
  float4 v = *(const float4*)(s + local);
  uint2 t; t.x = cvtpk(v.x, v.y); t.y = cvtpk(v.z, v.w);
  *(uint2*)(d + local) = t;
}

// ---------------- GEMM core: C[m][n] = sum_k A[m][k]*B[n][k] ----------------
// SWAP=false: acc reg r -> m (A rows), lane&15 -> n (verified R2).
// SWAP=true : operands swapped -> acc reg r -> n, lane&15 -> m (epilogue holds
//             4 consecutive n per lane for in-register RoPE).
template<bool SWAP>
__device__ __forceinline__ void gemm_core(const u16* __restrict__ A, const u16* __restrict__ Bw,
                                          u16* As, u16* Bs, f32x4 (&acc)[4][4]){
  const int tid = threadIdx.x, lane = tid & 63, wid = tid >> 6;
  const int m0 = blockIdx.y * 128, n0 = blockIdx.x * 128;
  const int wm = (wid >> 1) * 64, wn = (wid & 1) * 64;
  for (int k0 = 0; k0 < DM; k0 += 64){
    __syncthreads();
    #pragma unroll
    for (int i = 0; i < 4; i++){
      int row = i*32 + (tid >> 3);
      int cb  = (tid & 7) * 8;
      gl16(A  + (size_t)(m0+row)*DM + k0 + cb, (char*)As + i*4096 + tid*16);
      gl16(Bw + (size_t)(n0+row)*DM + k0 + cb, (char*)Bs + i*4096 + tid*16);
    }
    __syncthreads();
    #pragma unroll
    for (int kk = 0; kk < 2; kk++){
      const int co = kk*64 + (lane >> 4) * 16;
      bf16x8 af[4], bfr[4];
      #pragma unroll
      for (int mi = 0; mi < 4; mi++)
        af[mi] = *(const bf16x8*)((const char*)As + (wm + mi*16 + (lane & 15))*128 + co);
      #pragma unroll
      for (int ni = 0; ni < 4; ni++)
        bfr[ni] = *(const bf16x8*)((const char*)Bs + (wn + ni*16 + (lane & 15))*128 + co);
      #pragma unroll
      for (int mi = 0; mi < 4; mi++)
        #pragma unroll
        for (int ni = 0; ni < 4; ni++)
          acc[mi][ni] = SWAP ? mfma16(bfr[ni], af[mi], acc[mi][ni])
                             : mfma16(af[mi], bfr[ni], acc[mi][ni]);
    }
  }
}

// QKV GEMM with fused RoPE via trig table (fp32 rotation before bf16 pack).
__global__ __launch_bounds__(256) void k_gemm_qkv(const u16* __restrict__ xb, const u16* __restrict__ Wb,
                                                  u16* __restrict__ Qb, u16* __restrict__ Kb,
                                                  u16* __restrict__ Vb, const int* __restrict__ pos,
                                                  const float* __restrict__ tab){
  __shared__ __align__(16) u16 As[8192];
  __shared__ __align__(16) u16 Bs[8192];
  const int z = blockIdx.z;
  const u16* Bw = Wb + ((size_t)z << 20);
  u16* C = (z == 0) ? Qb : ((z == 1) ? Kb : Vb);
  f32x4 acc[4][4] = {};
  gemm_core<true>(xb, Bw, As, Bs, acc);
  const int lane = threadIdx.x & 63, wid = threadIdx.x >> 6;
  const int m0 = blockIdx.y*128 + (wid >> 1)*64, n0 = blockIdx.x*128 + (wid & 1)*64;
  const int ql = lane & 15, lg = lane >> 4;
  const bool dorope = (z < 2);
  const float4* tab4 = (const float4*)tab;     // [p][j/2] = {cos j, sin j, cos j+1, sin j+1}
  #pragma unroll
  for (int mi = 0; mi < 4; mi++){
    const int mrow = m0 + mi*16 + ql;
    const int p = pos[mrow & (SS-1)];
    #pragma unroll
    for (int ni = 0; ni < 4; ni++){
      const int nb = n0 + ni*16 + lg*4;        // 4 consecutive n, multiple of 4
      float o0 = acc[mi][ni][0], o1 = acc[mi][ni][1];
      float o2 = acc[mi][ni][2], o3 = acc[mi][ni][3];
      if (dorope){
        int j0 = (nb >> 1) & 31;               // even pair index within head
        float4 cs = tab4[p*16 + (j0 >> 1)];
        float t0 = o0*cs.x - o1*cs.y, t1 = o0*cs.y + o1*cs.x;
        o0 = t0; o1 = t1;
        t0 = o2*cs.z - o3*cs.w; t1 = o2*cs.w + o3*cs.z;
        o2 = t0; o3 = t1;
      }
      uint2 w; w.x = cvtpk(o0, o1); w.y = cvtpk(o2, o3);
      *(uint2*)(C + (size_t)mrow*DM + nb) = w;
    }
  }
}

__global__ __launch_bounds__(256) void k_gemm_out(const u16* __restrict__ AO, const u16* __restrict__ Wo,
                                                  float* __restrict__ Co){
  __shared__ __align__(16) u16 As[8192];
  __shared__ __align__(16) u16 Bs[8192];
  f32x4 acc[4][4] = {};
  gemm_core<false>(AO, Wo, As, Bs, acc);
  const int lane = threadIdx.x & 63, wid = threadIdx.x >> 6;
  const int m0 = blockIdx.y*128 + (wid >> 1)*64, n0 = blockIdx.x*128 + (wid & 1)*64;
  #pragma unroll
  for (int mi = 0; mi < 4; mi++)
    #pragma unroll
    for (int ni = 0; ni < 4; ni++)
      #pragma unroll
      for (int r = 0; r < 4; r++){
        int m = m0 + mi*16 + (lane >> 4)*4 + r;
        int n = n0 + ni*16 + (lane & 15);
        Co[(size_t)m*DM + n] = acc[mi][ni][r];
      }
}

// ---------------- flash attention, causal, 8-wave QBLK=128 (R5, verified 72.5us) ----
__global__ __launch_bounds__(512) void k_attn(const u16* __restrict__ Q, const u16* __restrict__ K,
                                              const u16* __restrict__ V, u16* __restrict__ AO){
  __shared__ __align__(16) u16 Ks[2][64*64];
  __shared__ __align__(16) u16 Vt[2][64*64];
  __shared__ __align__(16) u16 Ps[8][16*64];
  const int tid = threadIdx.x, lane = tid & 63, wid = tid >> 6;
  const int b = blockIdx.z, h = blockIdx.y;
  const int qb = b ? (15 - (int)blockIdx.x) : (int)blockIdx.x;   // balanced pairing
  const int qw = qb*128 + wid*16;
  const size_t base = ((size_t)b*SS)*DM + (size_t)h*DK;
  const int ql = lane & 15, lg = lane >> 4;
  const int NT = 2*qb + 2;

  const u16* qptr = Q + base + (size_t)(qw + ql)*DM + lg*8;
  bf16x8 qf0 = *(const bf16x8*)(qptr);
  bf16x8 qf1 = *(const bf16x8*)(qptr + 32);

  f32x4 oacc[4] = {};
  float m = -3e38f, lsum = 0.f;
  const float SC = 0.18033688011112042f;        // (1/sqrt(64)) * log2(e)
  const float THR = 8.0f / SC;

  const int skv = tid >> 3;
  const int sin = ((tid & 7) * 16) ^ ((skv & 7) << 4);
  const int kvl = (tid & 31)*2, dbase = (tid >> 5)*4;

  gl16(K + base + (size_t)skv*DM + (sin >> 1), (char*)Ks[0] + tid*16);
  {
    const u16* vsrc = V + base + (size_t)kvl*DM + dbase;
    ushort4 r0 = *(const ushort4*)(vsrc);
    ushort4 r1 = *(const ushort4*)(vsrc + DM);
    const u16 a0[4] = {r0.x, r0.y, r0.z, r0.w};
    const u16 a1[4] = {r1.x, r1.y, r1.z, r1.w};
    #pragma unroll
    for (int j = 0; j < 4; j++){
      int d = dbase + j;
      int byteoff = (d*128 + kvl*2) ^ ((d & 7) << 4);
      *(u32*)((char*)Vt[0] + byteoff) = (u32)a0[j] | ((u32)a1[j] << 16);
    }
  }
  __syncthreads();

  int cur = 0;
  for (int kt = 0; kt < NT; kt++){
    const int kv0 = kt*64;
    const bool more = (kt < NT-1);
    ushort4 vr0, vr1;
    if (more){
      const int kn0 = kv0 + 64;
      gl16(K + base + (size_t)(kn0+skv)*DM + (sin >> 1), (char*)Ks[cur^1] + tid*16);
      const u16* vsrc = V + base + (size_t)(kn0+kvl)*DM + dbase;
      vr0 = *(const ushort4*)(vsrc);
      vr1 = *(const ushort4*)(vsrc + DM);
    }

    const bool active = (kv0 <= qw + 15);
    if (active){
      f32x4 sf[4] = {};
      __builtin_amdgcn_s_setprio(1);
      #pragma unroll
      for (int kk = 0; kk < 2; kk++){
        const int co = kk*64 + lg*16;
        #pragma unroll
        for (int f = 0; f < 4; f++){
          int kvr = f*16 + ql;
          bf16x8 kf = *(const bf16x8*)((const char*)Ks[cur] + ((kvr*128 + co) ^ ((kvr & 7) << 4)));
          sf[f] = mfma16(kf, kk ? qf1 : qf0, sf[f]);
        }
      }
      __builtin_amdgcn_s_setprio(0);

      if (kv0 + 63 > qw){
        const int qa = qw + ql;
        #pragma unroll
        for (int f = 0; f < 4; f++)
          #pragma unroll
          for (int r = 0; r < 4; r++){
            int kva = kv0 + f*16 + lg*4 + r;
            sf[f][r] = (kva <= qa) ? sf[f][r] : -3e38f;
          }
      }

      float mx01 = fmaxf(fmaxf(sf[0][0], sf[0][1]), fmaxf(sf[0][2], sf[0][3]));
      float mx23 = fmaxf(fmaxf(sf[1][0], sf[1][1]), fmaxf(sf[1][2], sf[1][3]));
      float mx45 = fmaxf(fmaxf(sf[2][0], sf[2][1]), fmaxf(sf[2][2], sf[2][3]));
      float mx67 = fmaxf(fmaxf(sf[3][0], sf[3][1]), fmaxf(sf[3][2], sf[3][3]));
      float mx = fmaxf(fmaxf(mx01, mx23), fmaxf(mx45, mx67));

      if (!__all(mx <= m + THR)){
        mx = fmaxf(mx, __shfl_xor(mx, 16));
        mx = fmaxf(mx, __shfl_xor(mx, 32));
        const float mn = fmaxf(m, mx);
        const float alpha = exp2f((m - mn)*SC);
        #pragma unroll
        for (int ni = 0; ni < 4; ni++) oacc[ni] *= alpha;
        lsum *= alpha;
        m = mn;
      }

      const float nms = -m*SC;
      float p[4][4];
      float psum = 0.f;
      #pragma unroll
      for (int f = 0; f < 4; f++)
        #pragma unroll
        for (int r = 0; r < 4; r++){
          p[f][r] = exp2f(fmaf(sf[f][r], SC, nms));
          psum += p[f][r];
        }
      lsum += psum;

      #pragma unroll
      for (int f = 0; f < 4; f++)
        #pragma unroll
        for (int r = 0; r < 4; r += 2){
          int kv = f*16 + lg*4 + r;
          int byteoff = (ql*128 + kv*2) ^ ((ql & 7) << 4);
          *(u32*)((char*)Ps[wid] + byteoff) = cvtpk(p[f][r], p[f][r+1]);
        }

      __builtin_amdgcn_s_setprio(1);
      #pragma unroll
      for (int kk = 0; kk < 2; kk++){
        bf16x8 pf = *(const bf16x8*)((const char*)Ps[wid] +
                      ((ql*128 + kk*64 + lg*16) ^ ((ql & 7) << 4)));
        #pragma unroll
        for (int ni = 0; ni < 4; ni++){
          int d = ni*16 + ql;
          bf16x8 vf = *(const bf16x8*)((const char*)Vt[cur] +
                        ((d*128 + kk*64 + lg*16) ^ ((d & 7) << 4)));
          oacc[ni] = mfma16(vf, pf, oacc[ni]);
        }
      }
      __builtin_amdgcn_s_setprio(0);
    }

    if (more){
      const u16 a0[4] = {vr0.x, vr0.y, vr0.z, vr0.w};
      const u16 a1[4] = {vr1.x, vr1.y, vr1.z, vr1.w};
      #pragma unroll
      for (int j = 0; j < 4; j++){
        int d = dbase + j;
        int byteoff = (d*128 + kvl*2) ^ ((d & 7) << 4);
        *(u32*)((char*)Vt[cur^1] + byteoff) = (u32)a0[j] | ((u32)a1[j] << 16);
      }
    }
    __syncthreads();
    cur ^= 1;
  }

  lsum += __shfl_xor(lsum, 16);
  lsum += __shfl_xor(lsum, 32);
  const float rl = 1.0f / lsum;
  #pragma unroll
  for (int ni = 0; ni < 4; ni++)
    #pragma unroll
    for (int r = 0; r < 4; r += 2){
      int d = ni*16 + lg*4 + r;
      int byteoff = (ql*128 + d*2) ^ ((ql & 7) << 4);
      *(u32*)((char*)Ps[wid] + byteoff) = cvtpk(oacc[ni][r]*rl, oacc[ni][r+1]*rl);
    }
  #pragma unroll
  for (int pass = 0; pass < 2; pass++){
    int qr = pass*8 + (lane >> 3);
    int d0 = (lane & 7)*8;
    bf16x8 row = *(const bf16x8*)((const char*)Ps[wid] + ((qr*128 + d0*2) ^ ((qr & 7) << 4)));
    *(bf16x8*)(AO + base + (size_t)(qw + qr)*DM + d0) = row;
  }
}

// ---------------- launch ----------------
extern "C" void kernel_launch(void* const* d_in, const int* in_sizes, int n_in,
                              void* d_out, int out_size, void* d_ws, size_t ws_size,
                              hipStream_t stream){
  const float* x   = (const float*)d_in[0];
  const float* Wq  = (const float*)d_in[1];
  const float* Wk  = (const float*)d_in[2];
  const float* Wv  = (const float*)d_in[3];
  const float* Wo  = (const float*)d_in[4];
  const int*   pos = (const int*)d_in[5];
  float* out = (float*)d_out;

  const size_t NEED = ((size_t)41 << 20);   // 40 MiB buffers + 512 KiB trig table
  if (ws_size < NEED){
    hipMemsetAsync(d_out, 0x7f, (size_t)out_size * sizeof(float), stream);
    return;
  }

  char* ws = (char*)d_ws;
  u16* xb   = (u16*)(ws);
  u16* Wb   = (u16*)(ws + ((size_t)8  << 20));
  u16* Qb   = (u16*)(ws + ((size_t)16 << 20));
  u16* Kb   = (u16*)(ws + ((size_t)24 << 20));
  u16* Vb   = (u16*)(ws + ((size_t)32 << 20));
  float* tab = (float*)(ws + ((size_t)40 << 20));
  u16* AO = xb;

  k_cast<<<8448, 256, 0, stream>>>(x, Wq, Wk, Wv, Wo, xb, Wb, tab);
  k_gemm_qkv<<<dim3(8, 32, 3), 256, 0, stream>>>(xb, Wb, Qb, Kb, Vb, pos, tab);
  k_attn<<<dim3(16, 16, 2), 512, 0, stream>>>(Qb, Kb, Vb, AO);
  k_gemm_out<<<dim3(8, 32), 256, 0, stream>>>(AO, Wb + ((size_t)3 << 20), out);
}

// Round 8
// 148.219 us; speedup vs baseline: 1.1705x; 1.1049x over previous
//
#include <hip/hip_runtime.h>

#define DM 1024
#define NH 16
#define DK 64
#define BB 2
#define SS 2048

typedef unsigned short u16;
typedef unsigned int   u32;
typedef __bf16 bf16x8 __attribute__((ext_vector_type(8)));
typedef float  f32x4  __attribute__((ext_vector_type(4)));

__device__ __forceinline__ u16 f2bf(float f){
  u32 u = __float_as_uint(f);
  u32 r = (u + 0x7FFFu + ((u >> 16) & 1u)) >> 16;   // RNE
  return (u16)r;
}
__device__ __forceinline__ float bf2f(u16 v){ return __uint_as_float(((u32)v) << 16); }

// packed bf16 convert: low16 = bf16(lo), high16 = bf16(hi), RNE
__device__ __forceinline__ u32 cvtpk(float lo, float hi){
  u32 r;
  asm volatile("v_cvt_pk_bf16_f32 %0, %1, %2" : "=v"(r) : "v"(lo), "v"(hi));
  return r;
}

__device__ __forceinline__ void gl16(const void* g, void* l){
  __builtin_amdgcn_global_load_lds((const __attribute__((address_space(1))) u32*)g,
                                   (__attribute__((address_space(3))) u32*)l, 16, 0, 0);
}
__device__ __forceinline__ f32x4 mfma16(bf16x8 a, bf16x8 b, f32x4 c){
  return __builtin_amdgcn_mfma_f32_16x16x32_bf16(a, b, c, 0, 0, 0);
}

// ------- merged cast (x + 4 weights) + RoPE trig-table fill (tail blocks) -------
__global__ void k_cast(const float* __restrict__ x,  const float* __restrict__ wq,
                       const float* __restrict__ wk, const float* __restrict__ wv,
                       const float* __restrict__ wo, u16* __restrict__ xb,
                       u16* __restrict__ wb, float* __restrict__ tab){
  if (blockIdx.x >= 8192){
    int e = (blockIdx.x - 8192)*256 + threadIdx.x;   // [0, 65536)
    int p = e >> 5, j = e & 31;
    float s, c;
    sincosf((float)p * exp2f(-0.4152410118609203f * (float)j), &s, &c);
    float2 v; v.x = c; v.y = s;
    *(float2*)(tab + e*2) = v;
    return;
  }
  int e = blockIdx.x*1024 + threadIdx.x*4;
  int r = e >> 20;
  const float* s; u16* d; int local;
  if (r < 4){ s = x; d = xb; local = e; }
  else {
    const float* ws[4] = {wq, wk, wv, wo};
    int w = r - 4;
    local = e & 0xFFFFF;
    s = ws[w]; d = wb + ((size_t)w << 20);
  }
  float4 v = *(const float4*)(s + local);
  uint2 t; t.x = cvtpk(v.x, v.y); t.y = cvtpk(v.z, v.w);
  *(uint2*)(d + local) = t;
}

// ---------------- GEMM core: C[m][n] = sum_k A[m][k]*B[n][k] ----------------
// SWAP=false: acc reg r -> m (A rows), lane&15 -> n (verified R2).
// SWAP=true : acc reg r -> n, lane&15 -> m (verified via RoPE correctness R6/R7).
template<bool SWAP>
__device__ __forceinline__ void gemm_core(const u16* __restrict__ A, const u16* __restrict__ Bw,
                                          u16* As, u16* Bs, f32x4 (&acc)[4][4]){
  const int tid = threadIdx.x, lane = tid & 63, wid = tid >> 6;
  const int m0 = blockIdx.y * 128, n0 = blockIdx.x * 128;
  const int wm = (wid >> 1) * 64, wn = (wid & 1) * 64;
  for (int k0 = 0; k0 < DM; k0 += 64){
    __syncthreads();
    #pragma unroll
    for (int i = 0; i < 4; i++){
      int row = i*32 + (tid >> 3);
      int cb  = (tid & 7) * 8;
      gl16(A  + (size_t)(m0+row)*DM + k0 + cb, (char*)As + i*4096 + tid*16);
      gl16(Bw + (size_t)(n0+row)*DM + k0 + cb, (char*)Bs + i*4096 + tid*16);
    }
    __syncthreads();
    #pragma unroll
    for (int kk = 0; kk < 2; kk++){
      const int co = kk*64 + (lane >> 4) * 16;
      bf16x8 af[4], bfr[4];
      #pragma unroll
      for (int mi = 0; mi < 4; mi++)
        af[mi] = *(const bf16x8*)((const char*)As + (wm + mi*16 + (lane & 15))*128 + co);
      #pragma unroll
      for (int ni = 0; ni < 4; ni++)
        bfr[ni] = *(const bf16x8*)((const char*)Bs + (wn + ni*16 + (lane & 15))*128 + co);
      #pragma unroll
      for (int mi = 0; mi < 4; mi++)
        #pragma unroll
        for (int ni = 0; ni < 4; ni++)
          acc[mi][ni] = SWAP ? mfma16(bfr[ni], af[mi], acc[mi][ni])
                             : mfma16(af[mi], bfr[ni], acc[mi][ni]);
    }
  }
}

// QKV GEMM. z=0/1: fused RoPE (trig table), row-major out. z=2: V written
// TRANSPOSED as V^T[b][h*64+d][s]  (feature-major, so attn can gl16-stage it).
__global__ __launch_bounds__(256) void k_gemm_qkv(const u16* __restrict__ xb, const u16* __restrict__ Wb,
                                                  u16* __restrict__ Qb, u16* __restrict__ Kb,
                                                  u16* __restrict__ Vt_g, const int* __restrict__ pos,
                                                  const float* __restrict__ tab){
  __shared__ __align__(16) u16 As[8192];
  __shared__ __align__(16) u16 Bs[8192];
  const int z = blockIdx.z;
  const u16* Bw = Wb + ((size_t)z << 20);
  f32x4 acc[4][4] = {};
  gemm_core<true>(xb, Bw, As, Bs, acc);
  const int lane = threadIdx.x & 63, wid = threadIdx.x >> 6;
  const int m0 = blockIdx.y*128 + (wid >> 1)*64, n0 = blockIdx.x*128 + (wid & 1)*64;
  const int ql = lane & 15, lg = lane >> 4;

  if (z == 2){
    // transposed store: lane holds m = mrow (token), n = nb..nb+3 (feature).
    // V^T elem index = feature*SS + token  (feature = h*64+d = n).
    #pragma unroll
    for (int mi = 0; mi < 4; mi++){
      const int mrow = m0 + mi*16 + ql;
      const int bq = mrow >> 11, sq = mrow & (SS-1);
      u16* vt = Vt_g + ((size_t)bq*NH*DK)*SS + sq;
      #pragma unroll
      for (int ni = 0; ni < 4; ni++){
        const int nb = n0 + ni*16 + lg*4;
        #pragma unroll
        for (int r = 0; r < 4; r++)
          vt[(size_t)(nb + r)*SS] = f2bf(acc[mi][ni][r]);
      }
    }
    return;
  }

  u16* C = (z == 0) ? Qb : Kb;
  const float4* tab4 = (const float4*)tab;     // [p][j/2] = {cos j, sin j, cos j+1, sin j+1}
  #pragma unroll
  for (int mi = 0; mi < 4; mi++){
    const int mrow = m0 + mi*16 + ql;
    const int p = pos[mrow & (SS-1)];
    #pragma unroll
    for (int ni = 0; ni < 4; ni++){
      const int nb = n0 + ni*16 + lg*4;        // 4 consecutive n, multiple of 4
      float o0 = acc[mi][ni][0], o1 = acc[mi][ni][1];
      float o2 = acc[mi][ni][2], o3 = acc[mi][ni][3];
      int j0 = (nb >> 1) & 31;                 // even pair index within head
      float4 cs = tab4[p*16 + (j0 >> 1)];
      float t0 = o0*cs.x - o1*cs.y, t1 = o0*cs.y + o1*cs.x;
      o0 = t0; o1 = t1;
      t0 = o2*cs.z - o3*cs.w; t1 = o2*cs.w + o3*cs.z;
      o2 = t0; o3 = t1;
      uint2 w; w.x = cvtpk(o0, o1); w.y = cvtpk(o2, o3);
      *(uint2*)(C + (size_t)mrow*DM + nb) = w;
    }
  }
}

__global__ __launch_bounds__(256) void k_gemm_out(const u16* __restrict__ AO, const u16* __restrict__ Wo,
                                                  float* __restrict__ Co){
  __shared__ __align__(16) u16 As[8192];
  __shared__ __align__(16) u16 Bs[8192];
  f32x4 acc[4][4] = {};
  gemm_core<false>(AO, Wo, As, Bs, acc);
  const int lane = threadIdx.x & 63, wid = threadIdx.x >> 6;
  const int m0 = blockIdx.y*128 + (wid >> 1)*64, n0 = blockIdx.x*128 + (wid & 1)*64;
  #pragma unroll
  for (int mi = 0; mi < 4; mi++)
    #pragma unroll
    for (int ni = 0; ni < 4; ni++)
      #pragma unroll
      for (int r = 0; r < 4; r++){
        int m = m0 + mi*16 + (lane >> 4)*4 + r;
        int n = n0 + ni*16 + (lane & 15);
        Co[(size_t)m*DM + n] = acc[mi][ni][r];
      }
}

// ---------------- flash attention, causal, 8-wave QBLK=128 ----------------
// R8: V consumed from global V^T via gl16 (pre-swizzled source, linear LDS dest,
// swizzled read — both-sides pattern, same as K). Removes per-iter V reg-staging
// (2 loads + ~16 VALU + 4 ds_write + post-PV vmcnt wait). PV/QK^T code unchanged.
__global__ __launch_bounds__(512) void k_attn(const u16* __restrict__ Q, const u16* __restrict__ K,
                                              const u16* __restrict__ Vt_g, u16* __restrict__ AO){
  __shared__ __align__(16) u16 Ks[2][64*64];
  __shared__ __align__(16) u16 Vt[2][64*64];
  __shared__ __align__(16) u16 Ps[8][16*64];
  const int tid = threadIdx.x, lane = tid & 63, wid = tid >> 6;
  const int b = blockIdx.z, h = blockIdx.y;
  const int qb = b ? (15 - (int)blockIdx.x) : (int)blockIdx.x;   // balanced pairing
  const int qw = qb*128 + wid*16;
  const size_t base = ((size_t)b*SS)*DM + (size_t)h*DK;
  const size_t vtb  = ((size_t)b*NH + h)*DK*SS;                  // V^T base
  const int ql = lane & 15, lg = lane >> 4;
  const int NT = 2*qb + 2;

  const u16* qptr = Q + base + (size_t)(qw + ql)*DM + lg*8;
  bf16x8 qf0 = *(const bf16x8*)(qptr);
  bf16x8 qf1 = *(const bf16x8*)(qptr + 32);

  f32x4 oacc[4] = {};
  float m = -3e38f, lsum = 0.f;
  const float SC = 0.18033688011112042f;        // (1/sqrt(64)) * log2(e)
  const float THR = 8.0f / SC;

  // staging: one gl16 per thread per tensor. srow = kv row (K) / d row (V^T).
  const int srow = tid >> 3;
  const int sin = ((tid & 7) * 16) ^ ((srow & 7) << 4);   // pre-swizzled byte col

  gl16(K    + base + (size_t)srow*DM + (sin >> 1), (char*)Ks[0] + tid*16);
  gl16(Vt_g + vtb  + (size_t)srow*SS + (sin >> 1), (char*)Vt[0] + tid*16);
  __syncthreads();

  int cur = 0;
  for (int kt = 0; kt < NT; kt++){
    const int kv0 = kt*64;
    const bool more = (kt < NT-1);
    if (more){
      const int kn0 = kv0 + 64;
      gl16(K    + base + (size_t)(kn0+srow)*DM + (sin >> 1), (char*)Ks[cur^1] + tid*16);
      gl16(Vt_g + vtb  + (size_t)srow*SS + kn0 + (sin >> 1), (char*)Vt[cur^1] + tid*16);
    }

    const bool active = (kv0 <= qw + 15);
    if (active){
      f32x4 sf[4] = {};
      __builtin_amdgcn_s_setprio(1);
      #pragma unroll
      for (int kk = 0; kk < 2; kk++){
        const int co = kk*64 + lg*16;
        #pragma unroll
        for (int f = 0; f < 4; f++){
          int kvr = f*16 + ql;
          bf16x8 kf = *(const bf16x8*)((const char*)Ks[cur] + ((kvr*128 + co) ^ ((kvr & 7) << 4)));
          sf[f] = mfma16(kf, kk ? qf1 : qf0, sf[f]);
        }
      }
      __builtin_amdgcn_s_setprio(0);

      if (kv0 + 63 > qw){
        const int qa = qw + ql;
        #pragma unroll
        for (int f = 0; f < 4; f++)
          #pragma unroll
          for (int r = 0; r < 4; r++){
            int kva = kv0 + f*16 + lg*4 + r;
            sf[f][r] = (kva <= qa) ? sf[f][r] : -3e38f;
          }
      }

      float mx01 = fmaxf(fmaxf(sf[0][0], sf[0][1]), fmaxf(sf[0][2], sf[0][3]));
      float mx23 = fmaxf(fmaxf(sf[1][0], sf[1][1]), fmaxf(sf[1][2], sf[1][3]));
      float mx45 = fmaxf(fmaxf(sf[2][0], sf[2][1]), fmaxf(sf[2][2], sf[2][3]));
      float mx67 = fmaxf(fmaxf(sf[3][0], sf[3][1]), fmaxf(sf[3][2], sf[3][3]));
      float mx = fmaxf(fmaxf(mx01, mx23), fmaxf(mx45, mx67));

      if (!__all(mx <= m + THR)){               // defer-max
        mx = fmaxf(mx, __shfl_xor(mx, 16));
        mx = fmaxf(mx, __shfl_xor(mx, 32));
        const float mn = fmaxf(m, mx);
        const float alpha = exp2f((m - mn)*SC);
        #pragma unroll
        for (int ni = 0; ni < 4; ni++) oacc[ni] *= alpha;
        lsum *= alpha;
        m = mn;
      }

      const float nms = -m*SC;
      float p[4][4];
      float psum = 0.f;
      #pragma unroll
      for (int f = 0; f < 4; f++)
        #pragma unroll
        for (int r = 0; r < 4; r++){
          p[f][r] = exp2f(fmaf(sf[f][r], SC, nms));
          psum += p[f][r];
        }
      lsum += psum;

      #pragma unroll
      for (int f = 0; f < 4; f++)
        #pragma unroll
        for (int r = 0; r < 4; r += 2){
          int kv = f*16 + lg*4 + r;
          int byteoff = (ql*128 + kv*2) ^ ((ql & 7) << 4);
          *(u32*)((char*)Ps[wid] + byteoff) = cvtpk(p[f][r], p[f][r+1]);
        }

      __builtin_amdgcn_s_setprio(1);
      #pragma unroll
      for (int kk = 0; kk < 2; kk++){
        bf16x8 pf = *(const bf16x8*)((const char*)Ps[wid] +
                      ((ql*128 + kk*64 + lg*16) ^ ((ql & 7) << 4)));
        #pragma unroll
        for (int ni = 0; ni < 4; ni++){
          int d = ni*16 + ql;
          bf16x8 vf = *(const bf16x8*)((const char*)Vt[cur] +
                        ((d*128 + kk*64 + lg*16) ^ ((d & 7) << 4)));
          oacc[ni] = mfma16(vf, pf, oacc[ni]);
        }
      }
      __builtin_amdgcn_s_setprio(0);
    }

    __syncthreads();
    cur ^= 1;
  }

  lsum += __shfl_xor(lsum, 16);
  lsum += __shfl_xor(lsum, 32);
  const float rl = 1.0f / lsum;
  #pragma unroll
  for (int ni = 0; ni < 4; ni++)
    #pragma unroll
    for (int r = 0; r < 4; r += 2){
      int d = ni*16 + lg*4 + r;
      int byteoff = (ql*128 + d*2) ^ ((ql & 7) << 4);
      *(u32*)((char*)Ps[wid] + byteoff) = cvtpk(oacc[ni][r]*rl, oacc[ni][r+1]*rl);
    }
  #pragma unroll
  for (int pass = 0; pass < 2; pass++){
    int qr = pass*8 + (lane >> 3);
    int d0 = (lane & 7)*8;
    bf16x8 row = *(const bf16x8*)((const char*)Ps[wid] + ((qr*128 + d0*2) ^ ((qr & 7) << 4)));
    *(bf16x8*)(AO + base + (size_t)(qw + qr)*DM + d0) = row;
  }
}

// ---------------- launch ----------------
extern "C" void kernel_launch(void* const* d_in, const int* in_sizes, int n_in,
                              void* d_out, int out_size, void* d_ws, size_t ws_size,
                              hipStream_t stream){
  const float* x   = (const float*)d_in[0];
  const float* Wq  = (const float*)d_in[1];
  const float* Wk  = (const float*)d_in[2];
  const float* Wv  = (const float*)d_in[3];
  const float* Wo  = (const float*)d_in[4];
  const int*   pos = (const int*)d_in[5];
  float* out = (float*)d_out;

  const size_t NEED = ((size_t)41 << 20);   // 40 MiB buffers + 512 KiB trig table
  if (ws_size < NEED){
    hipMemsetAsync(d_out, 0x7f, (size_t)out_size * sizeof(float), stream);
    return;
  }

  char* ws = (char*)d_ws;
  u16* xb   = (u16*)(ws);
  u16* Wb   = (u16*)(ws + ((size_t)8  << 20));
  u16* Qb   = (u16*)(ws + ((size_t)16 << 20));
  u16* Kb   = (u16*)(ws + ((size_t)24 << 20));
  u16* Vt   = (u16*)(ws + ((size_t)32 << 20));   // V^T [b][h*64+d][s]
  float* tab = (float*)(ws + ((size_t)40 << 20));
  u16* AO = xb;

  k_cast<<<8448, 256, 0, stream>>>(x, Wq, Wk, Wv, Wo, xb, Wb, tab);
  k_gemm_qkv<<<dim3(8, 32, 3), 256, 0, stream>>>(xb, Wb, Qb, Kb, Vt, pos, tab);
  k_attn<<<dim3(16, 16, 2), 512, 0, stream>>>(Qb, Kb, Vt, AO);
  k_gemm_out<<<dim3(8, 32), 256, 0, stream>>>(AO, Wb + ((size_t)3 << 20), out);
}

// Round 9
// 147.314 us; speedup vs baseline: 1.1777x; 1.0061x over previous
//
#include <hip/hip_runtime.h>

#define DM 1024
#define NH 16
#define DK 64
#define BB 2
#define SS 2048

typedef unsigned short u16;
typedef unsigned int   u32;
typedef __bf16 bf16x8 __attribute__((ext_vector_type(8)));
typedef float  f32x4  __attribute__((ext_vector_type(4)));

__device__ __forceinline__ u16 f2bf(float f){
  u32 u = __float_as_uint(f);
  u32 r = (u + 0x7FFFu + ((u >> 16) & 1u)) >> 16;   // RNE
  return (u16)r;
}
__device__ __forceinline__ float bf2f(u16 v){ return __uint_as_float(((u32)v) << 16); }

// packed bf16 convert: low16 = bf16(lo), high16 = bf16(hi), RNE
__device__ __forceinline__ u32 cvtpk(float lo, float hi){
  u32 r;
  asm volatile("v_cvt_pk_bf16_f32 %0, %1, %2" : "=v"(r) : "v"(lo), "v"(hi));
  return r;
}

__device__ __forceinline__ void gl16(const void* g, void* l){
  __builtin_amdgcn_global_load_lds((const __attribute__((address_space(1))) u32*)g,
                                   (__attribute__((address_space(3))) u32*)l, 16, 0, 0);
}
__device__ __forceinline__ f32x4 mfma16(bf16x8 a, bf16x8 b, f32x4 c){
  return __builtin_amdgcn_mfma_f32_16x16x32_bf16(a, b, c, 0, 0, 0);
}

// ------- merged cast (x + 4 weights) + RoPE trig-table fill (tail blocks) -------
__global__ void k_cast(const float* __restrict__ x,  const float* __restrict__ wq,
                       const float* __restrict__ wk, const float* __restrict__ wv,
                       const float* __restrict__ wo, u16* __restrict__ xb,
                       u16* __restrict__ wb, float* __restrict__ tab){
  if (blockIdx.x >= 8192){
    int e = (blockIdx.x - 8192)*256 + threadIdx.x;   // [0, 65536)
    int p = e >> 5, j = e & 31;
    float s, c;
    sincosf((float)p * exp2f(-0.4152410118609203f * (float)j), &s, &c);
    float2 v; v.x = c; v.y = s;
    *(float2*)(tab + e*2) = v;
    return;
  }
  int e = blockIdx.x*1024 + threadIdx.x*4;
  int r = e >> 20;
  const float* s; u16* d; int local;
  if (r < 4){ s = x; d = xb; local = e; }
  else {
    const float* ws[4] = {wq, wk, wv, wo};
    int w = r - 4;
    local = e & 0xFFFFF;
    s = ws[w]; d = wb + ((size_t)w << 20);
  }
  float4 v = *(const float4*)(s + local);
  uint2 t; t.x = cvtpk(v.x, v.y); t.y = cvtpk(v.z, v.w);
  *(uint2*)(d + local) = t;
}

// ---------------- GEMM core R9: BK=32, double-buffered, swizzled, 1 barrier/iter --
// Unified LDS tile: [128 rows][128B], row r = A-row(64B) || B-row(64B), byte-swizzled
// by ^((r&7)<<4) (8 x 16B slots, bijective). Staged via gl16 with PRE-SWIZZLED global
// source (linear LDS dest). A-frag slot lg^(r&7), B-frag slot (4+lg)^(r&7) - disjoint.
// Loop: issue gl16(tile t+1) -> compute tile t -> one __syncthreads (drains vmcnt
// AFTER compute phase -> HBM latency hidden, attn-style).
// SWAP=false: acc reg r -> m, lane&15 -> n (verified R2).
// SWAP=true : acc reg r -> n, lane&15 -> m (verified via RoPE correctness R6/R7).
template<bool SWAP>
__device__ __forceinline__ void gemm_core(const u16* __restrict__ A, const u16* __restrict__ Bw,
                                          u16* S, f32x4 (&acc)[4][4]){
  const int tid = threadIdx.x, lane = tid & 63, wid = tid >> 6;
  const int m0 = blockIdx.y * 128, n0 = blockIdx.x * 128;
  const int wm = (wid >> 1) * 64, wn = (wid & 1) * 64;
  const int ql = lane & 15, lg = lane >> 4;

  // staging decode (compile-time per i): L = i*4096 + tid*16
  //   r = L>>7, slot = (L>>4)&7, orig = slot ^ (r&7)
  //   orig<4 -> A[m0+r][k0 + orig*8 ..], else B[n0+r][k0 + (orig-4)*8 ..]
  #define STAGE_QKV(buf, k0)                                                     \
    _Pragma("unroll")                                                            \
    for (int i = 0; i < 4; i++){                                                 \
      int L = i*4096 + tid*16;                                                   \
      int r_ = L >> 7;                                                           \
      int orig = ((L >> 4) & 7) ^ (r_ & 7);                                      \
      const u16* src = (orig < 4)                                                \
          ? (A  + (size_t)(m0 + r_)*DM + (k0) + orig*8)                          \
          : (Bw + (size_t)(n0 + r_)*DM + (k0) + (orig - 4)*8);                   \
      gl16(src, (char*)(buf) + L);                                               \
    }

  char* Sb[2] = {(char*)S, (char*)S + 16384};

  STAGE_QKV(Sb[0], 0);
  __syncthreads();

  int cur = 0;
  #pragma unroll 1
  for (int t = 0; t < 32; t++){
    if (t < 31){ STAGE_QKV(Sb[cur^1], (t+1)*32); }

    bf16x8 af[4], bfr[4];
    #pragma unroll
    for (int mi = 0; mi < 4; mi++){
      int r = wm + mi*16 + ql;
      af[mi] = *(const bf16x8*)(Sb[cur] + r*128 + ((lg*16) ^ ((r & 7) << 4)));
    }
    #pragma unroll
    for (int ni = 0; ni < 4; ni++){
      int r = wn + ni*16 + ql;
      bfr[ni] = *(const bf16x8*)(Sb[cur] + r*128 + ((64 + lg*16) ^ ((r & 7) << 4)));
    }
    __builtin_amdgcn_s_setprio(1);
    #pragma unroll
    for (int mi = 0; mi < 4; mi++)
      #pragma unroll
      for (int ni = 0; ni < 4; ni++)
        acc[mi][ni] = SWAP ? mfma16(bfr[ni], af[mi], acc[mi][ni])
                           : mfma16(af[mi], bfr[ni], acc[mi][ni]);
    __builtin_amdgcn_s_setprio(0);

    __syncthreads();          // drains vmcnt (t+1 loads) AFTER compute; protects LDS flip
    cur ^= 1;
  }
  #undef STAGE_QKV
}

// QKV GEMM. z=0/1: fused RoPE (trig table), row-major out. z=2: V written
// TRANSPOSED as V^T[b][h*64+d][s]  (feature-major, so attn can gl16-stage it).
__global__ __launch_bounds__(256) void k_gemm_qkv(const u16* __restrict__ xb, const u16* __restrict__ Wb,
                                                  u16* __restrict__ Qb, u16* __restrict__ Kb,
                                                  u16* __restrict__ Vt_g, const int* __restrict__ pos,
                                                  const float* __restrict__ tab){
  __shared__ __align__(16) u16 S[2*8192];
  const int z = blockIdx.z;
  const u16* Bw = Wb + ((size_t)z << 20);
  f32x4 acc[4][4] = {};
  gemm_core<true>(xb, Bw, S, acc);
  const int lane = threadIdx.x & 63, wid = threadIdx.x >> 6;
  const int m0 = blockIdx.y*128 + (wid >> 1)*64, n0 = blockIdx.x*128 + (wid & 1)*64;
  const int ql = lane & 15, lg = lane >> 4;

  if (z == 2){
    #pragma unroll
    for (int mi = 0; mi < 4; mi++){
      const int mrow = m0 + mi*16 + ql;
      const int bq = mrow >> 11, sq = mrow & (SS-1);
      u16* vt = Vt_g + ((size_t)bq*NH*DK)*SS + sq;
      #pragma unroll
      for (int ni = 0; ni < 4; ni++){
        const int nb = n0 + ni*16 + lg*4;
        #pragma unroll
        for (int r = 0; r < 4; r++)
          vt[(size_t)(nb + r)*SS] = f2bf(acc[mi][ni][r]);
      }
    }
    return;
  }

  u16* C = (z == 0) ? Qb : Kb;
  const float4* tab4 = (const float4*)tab;     // [p][j/2] = {cos j, sin j, cos j+1, sin j+1}
  #pragma unroll
  for (int mi = 0; mi < 4; mi++){
    const int mrow = m0 + mi*16 + ql;
    const int p = pos[mrow & (SS-1)];
    #pragma unroll
    for (int ni = 0; ni < 4; ni++){
      const int nb = n0 + ni*16 + lg*4;        // 4 consecutive n, multiple of 4
      float o0 = acc[mi][ni][0], o1 = acc[mi][ni][1];
      float o2 = acc[mi][ni][2], o3 = acc[mi][ni][3];
      int j0 = (nb >> 1) & 31;                 // even pair index within head
      float4 cs = tab4[p*16 + (j0 >> 1)];
      float t0 = o0*cs.x - o1*cs.y, t1 = o0*cs.y + o1*cs.x;
      o0 = t0; o1 = t1;
      t0 = o2*cs.z - o3*cs.w; t1 = o2*cs.w + o3*cs.z;
      o2 = t0; o3 = t1;
      uint2 w; w.x = cvtpk(o0, o1); w.y = cvtpk(o2, o3);
      *(uint2*)(C + (size_t)mrow*DM + nb) = w;
    }
  }
}

__global__ __launch_bounds__(256) void k_gemm_out(const u16* __restrict__ AO, const u16* __restrict__ Wo,
                                                  float* __restrict__ Co){
  __shared__ __align__(16) u16 S[2*8192];
  f32x4 acc[4][4] = {};
  gemm_core<false>(AO, Wo, S, acc);
  const int lane = threadIdx.x & 63, wid = threadIdx.x >> 6;
  const int m0 = blockIdx.y*128 + (wid >> 1)*64, n0 = blockIdx.x*128 + (wid & 1)*64;
  #pragma unroll
  for (int mi = 0; mi < 4; mi++)
    #pragma unroll
    for (int ni = 0; ni < 4; ni++)
      #pragma unroll
      for (int r = 0; r < 4; r++){
        int m = m0 + mi*16 + (lane >> 4)*4 + r;
        int n = n0 + ni*16 + (lane & 15);
        Co[(size_t)m*DM + n] = acc[mi][ni][r];
      }
}

// ---------------- flash attention, causal, 8-wave QBLK=128 (R8, verified) ----------
__global__ __launch_bounds__(512) void k_attn(const u16* __restrict__ Q, const u16* __restrict__ K,
                                              const u16* __restrict__ Vt_g, u16* __restrict__ AO){
  __shared__ __align__(16) u16 Ks[2][64*64];
  __shared__ __align__(16) u16 Vt[2][64*64];
  __shared__ __align__(16) u16 Ps[8][16*64];
  const int tid = threadIdx.x, lane = tid & 63, wid = tid >> 6;
  const int b = blockIdx.z, h = blockIdx.y;
  const int qb = b ? (15 - (int)blockIdx.x) : (int)blockIdx.x;   // balanced pairing
  const int qw = qb*128 + wid*16;
  const size_t base = ((size_t)b*SS)*DM + (size_t)h*DK;
  const size_t vtb  = ((size_t)b*NH + h)*DK*SS;                  // V^T base
  const int ql = lane & 15, lg = lane >> 4;
  const int NT = 2*qb + 2;

  const u16* qptr = Q + base + (size_t)(qw + ql)*DM + lg*8;
  bf16x8 qf0 = *(const bf16x8*)(qptr);
  bf16x8 qf1 = *(const bf16x8*)(qptr + 32);

  f32x4 oacc[4] = {};
  float m = -3e38f, lsum = 0.f;
  const float SC = 0.18033688011112042f;        // (1/sqrt(64)) * log2(e)
  const float THR = 8.0f / SC;

  const int srow = tid >> 3;
  const int sin = ((tid & 7) * 16) ^ ((srow & 7) << 4);   // pre-swizzled byte col

  gl16(K    + base + (size_t)srow*DM + (sin >> 1), (char*)Ks[0] + tid*16);
  gl16(Vt_g + vtb  + (size_t)srow*SS + (sin >> 1), (char*)Vt[0] + tid*16);
  __syncthreads();

  int cur = 0;
  for (int kt = 0; kt < NT; kt++){
    const int kv0 = kt*64;
    const bool more = (kt < NT-1);
    if (more){
      const int kn0 = kv0 + 64;
      gl16(K    + base + (size_t)(kn0+srow)*DM + (sin >> 1), (char*)Ks[cur^1] + tid*16);
      gl16(Vt_g + vtb  + (size_t)srow*SS + kn0 + (sin >> 1), (char*)Vt[cur^1] + tid*16);
    }

    const bool active = (kv0 <= qw + 15);
    if (active){
      f32x4 sf[4] = {};
      __builtin_amdgcn_s_setprio(1);
      #pragma unroll
      for (int kk = 0; kk < 2; kk++){
        const int co = kk*64 + lg*16;
        #pragma unroll
        for (int f = 0; f < 4; f++){
          int kvr = f*16 + ql;
          bf16x8 kf = *(const bf16x8*)((const char*)Ks[cur] + ((kvr*128 + co) ^ ((kvr & 7) << 4)));
          sf[f] = mfma16(kf, kk ? qf1 : qf0, sf[f]);
        }
      }
      __builtin_amdgcn_s_setprio(0);

      if (kv0 + 63 > qw){
        const int qa = qw + ql;
        #pragma unroll
        for (int f = 0; f < 4; f++)
          #pragma unroll
          for (int r = 0; r < 4; r++){
            int kva = kv0 + f*16 + lg*4 + r;
            sf[f][r] = (kva <= qa) ? sf[f][r] : -3e38f;
          }
      }

      float mx01 = fmaxf(fmaxf(sf[0][0], sf[0][1]), fmaxf(sf[0][2], sf[0][3]));
      float mx23 = fmaxf(fmaxf(sf[1][0], sf[1][1]), fmaxf(sf[1][2], sf[1][3]));
      float mx45 = fmaxf(fmaxf(sf[2][0], sf[2][1]), fmaxf(sf[2][2], sf[2][3]));
      float mx67 = fmaxf(fmaxf(sf[3][0], sf[3][1]), fmaxf(sf[3][2], sf[3][3]));
      float mx = fmaxf(fmaxf(mx01, mx23), fmaxf(mx45, mx67));

      if (!__all(mx <= m + THR)){               // defer-max
        mx = fmaxf(mx, __shfl_xor(mx, 16));
        mx = fmaxf(mx, __shfl_xor(mx, 32));
        const float mn = fmaxf(m, mx);
        const float alpha = exp2f((m - mn)*SC);
        #pragma unroll
        for (int ni = 0; ni < 4; ni++) oacc[ni] *= alpha;
        lsum *= alpha;
        m = mn;
      }

      const float nms = -m*SC;
      float p[4][4];
      float psum = 0.f;
      #pragma unroll
      for (int f = 0; f < 4; f++)
        #pragma unroll
        for (int r = 0; r < 4; r++){
          p[f][r] = exp2f(fmaf(sf[f][r], SC, nms));
          psum += p[f][r];
        }
      lsum += psum;

      #pragma unroll
      for (int f = 0; f < 4; f++)
        #pragma unroll
        for (int r = 0; r < 4; r += 2){
          int kv = f*16 + lg*4 + r;
          int byteoff = (ql*128 + kv*2) ^ ((ql & 7) << 4);
          *(u32*)((char*)Ps[wid] + byteoff) = cvtpk(p[f][r], p[f][r+1]);
        }

      __builtin_amdgcn_s_setprio(1);
      #pragma unroll
      for (int kk = 0; kk < 2; kk++){
        bf16x8 pf = *(const bf16x8*)((const char*)Ps[wid] +
                      ((ql*128 + kk*64 + lg*16) ^ ((ql & 7) << 4)));
        #pragma unroll
        for (int ni = 0; ni < 4; ni++){
          int d = ni*16 + ql;
          bf16x8 vf = *(const bf16x8*)((const char*)Vt[cur] +
                        ((d*128 + kk*64 + lg*16) ^ ((d & 7) << 4)));
          oacc[ni] = mfma16(vf, pf, oacc[ni]);
        }
      }
      __builtin_amdgcn_s_setprio(0);
    }

    __syncthreads();
    cur ^= 1;
  }

  lsum += __shfl_xor(lsum, 16);
  lsum += __shfl_xor(lsum, 32);
  const float rl = 1.0f / lsum;
  #pragma unroll
  for (int ni = 0; ni < 4; ni++)
    #pragma unroll
    for (int r = 0; r < 4; r += 2){
      int d = ni*16 + lg*4 + r;
      int byteoff = (ql*128 + d*2) ^ ((ql & 7) << 4);
      *(u32*)((char*)Ps[wid] + byteoff) = cvtpk(oacc[ni][r]*rl, oacc[ni][r+1]*rl);
    }
  #pragma unroll
  for (int pass = 0; pass < 2; pass++){
    int qr = pass*8 + (lane >> 3);
    int d0 = (lane & 7)*8;
    bf16x8 row = *(const bf16x8*)((const char*)Ps[wid] + ((qr*128 + d0*2) ^ ((qr & 7) << 4)));
    *(bf16x8*)(AO + base + (size_t)(qw + qr)*DM + d0) = row;
  }
}

// ---------------- launch ----------------
extern "C" void kernel_launch(void* const* d_in, const int* in_sizes, int n_in,
                              void* d_out, int out_size, void* d_ws, size_t ws_size,
                              hipStream_t stream){
  const float* x   = (const float*)d_in[0];
  const float* Wq  = (const float*)d_in[1];
  const float* Wk  = (const float*)d_in[2];
  const float* Wv  = (const float*)d_in[3];
  const float* Wo  = (const float*)d_in[4];
  const int*   pos = (const int*)d_in[5];
  float* out = (float*)d_out;

  const size_t NEED = ((size_t)41 << 20);   // 40 MiB buffers + 512 KiB trig table
  if (ws_size < NEED){
    hipMemsetAsync(d_out, 0x7f, (size_t)out_size * sizeof(float), stream);
    return;
  }

  char* ws = (char*)d_ws;
  u16* xb   = (u16*)(ws);
  u16* Wb   = (u16*)(ws + ((size_t)8  << 20));
  u16* Qb   = (u16*)(ws + ((size_t)16 << 20));
  u16* Kb   = (u16*)(ws + ((size_t)24 << 20));
  u16* Vt   = (u16*)(ws + ((size_t)32 << 20));   // V^T [b][h*64+d][s]
  float* tab = (float*)(ws + ((size_t)40 << 20));
  u16* AO = xb;

  k_cast<<<8448, 256, 0, stream>>>(x, Wq, Wk, Wv, Wo, xb, Wb, tab);
  k_gemm_qkv<<<dim3(8, 32, 3), 256, 0, stream>>>(xb, Wb, Qb, Kb, Vt, pos, tab);
  k_attn<<<dim3(16, 16, 2), 512, 0, stream>>>(Qb, Kb, Vt, AO);
  k_gemm_out<<<dim3(8, 32), 256, 0, stream>>>(AO, Wb + ((size_t)3 << 20), out);
}

// Round 10
// 123.566 us; speedup vs baseline: 1.4040x; 1.1922x over previous
//
#include <hip/hip_runtime.h>

#define DM 1024
#define NH 16
#define DK 64
#define BB 2
#define SS 2048

typedef unsigned short u16;
typedef unsigned int   u32;
typedef __bf16 bf16x8 __attribute__((ext_vector_type(8)));
typedef float  f32x4  __attribute__((ext_vector_type(4)));

__device__ __forceinline__ u16 f2bf(float f){
  u32 u = __float_as_uint(f);
  u32 r = (u + 0x7FFFu + ((u >> 16) & 1u)) >> 16;   // RNE
  return (u16)r;
}
__device__ __forceinline__ float bf2f(u16 v){ return __uint_as_float(((u32)v) << 16); }

// packed bf16 convert: low16 = bf16(lo), high16 = bf16(hi), RNE
__device__ __forceinline__ u32 cvtpk(float lo, float hi){
  u32 r;
  asm volatile("v_cvt_pk_bf16_f32 %0, %1, %2" : "=v"(r) : "v"(lo), "v"(hi));
  return r;
}

__device__ __forceinline__ void gl16(const void* g, void* l){
  __builtin_amdgcn_global_load_lds((const __attribute__((address_space(1))) u32*)g,
                                   (__attribute__((address_space(3))) u32*)l, 16, 0, 0);
}
__device__ __forceinline__ f32x4 mfma16(bf16x8 a, bf16x8 b, f32x4 c){
  return __builtin_amdgcn_mfma_f32_16x16x32_bf16(a, b, c, 0, 0, 0);
}

// ------- merged cast (x + 4 weights) + RoPE trig-table fill (tail blocks) -------
__global__ void k_cast(const float* __restrict__ x,  const float* __restrict__ wq,
                       const float* __restrict__ wk, const float* __restrict__ wv,
                       const float* __restrict__ wo, u16* __restrict__ xb,
                       u16* __restrict__ wb, float* __restrict__ tab){
  if (blockIdx.x >= 8192){
    int e = (blockIdx.x - 8192)*256 + threadIdx.x;   // [0, 65536)
    int p = e >> 5, j = e & 31;
    float s, c;
    sincosf((float)p * exp2f(-0.4152410118609203f * (float)j), &s, &c);
    float2 v; v.x = c; v.y = s;
    *(float2*)(tab + e*2) = v;
    return;
  }
  int e = blockIdx.x*1024 + threadIdx.x*4;
  int r = e >> 20;
  const float* s; u16* d; int local;
  if (r < 4){ s = x; d = xb; local = e; }
  else {
    const float* ws[4] = {wq, wk, wv, wo};
    int w = r - 4;
    local = e & 0xFFFFF;
    s = ws[w]; d = wb + ((size_t)w << 20);
  }
  float4 v = *(const float4*)(s + local);
  uint2 t; t.x = cvtpk(v.x, v.y); t.y = cvtpk(v.z, v.w);
  *(uint2*)(d + local) = t;
}

// ---------------- GEMM core R10: BK=32, TRIPLE-buffered, counted vmcnt (T4) -------
// Per iter: s_waitcnt vmcnt(4) [my stage(t) done, stage(t+1) in flight] -> s_barrier
// [all waves' stage(t) done] -> issue stage(t+2) -> compute(t). Loads stay in flight
// ~2 iterations; vmcnt never drains to 0 in the main loop (m218's isolated lever).
// LDS tile: [128 rows][128B], row r = A(64B) || B(64B), byte-swizzle ^((r&7)<<4),
// staged via gl16 with pre-swizzled global source (R9-verified, conflicts = 0).
// SWAP=false: acc reg r -> m, lane&15 -> n. SWAP=true: reg r -> n, lane&15 -> m.
template<bool SWAP>
__device__ __forceinline__ void gemm_core(const u16* __restrict__ A, const u16* __restrict__ Bw,
                                          u16* S, f32x4 (&acc)[4][4]){
  const int tid = threadIdx.x, lane = tid & 63, wid = tid >> 6;
  const int m0 = blockIdx.y * 128, n0 = blockIdx.x * 128;
  const int wm = (wid >> 1) * 64, wn = (wid & 1) * 64;
  const int ql = lane & 15, lg = lane >> 4;

  #define STAGE_G(buf, k0)                                                       \
    _Pragma("unroll")                                                            \
    for (int i = 0; i < 4; i++){                                                 \
      int L = i*4096 + tid*16;                                                   \
      int r_ = L >> 7;                                                           \
      int orig = ((L >> 4) & 7) ^ (r_ & 7);                                      \
      const u16* src = (orig < 4)                                                \
          ? (A  + (size_t)(m0 + r_)*DM + (k0) + orig*8)                          \
          : (Bw + (size_t)(n0 + r_)*DM + (k0) + (orig - 4)*8);                   \
      gl16(src, (char*)(buf) + L);                                               \
    }

  #define COMPUTE_T(buf)                                                         \
    {                                                                            \
      bf16x8 af[4], bfr[4];                                                      \
      _Pragma("unroll")                                                          \
      for (int mi = 0; mi < 4; mi++){                                            \
        int r = wm + mi*16 + ql;                                                 \
        af[mi] = *(const bf16x8*)((char*)(buf) + r*128 + ((lg*16) ^ ((r & 7) << 4))); \
      }                                                                          \
      _Pragma("unroll")                                                          \
      for (int ni = 0; ni < 4; ni++){                                            \
        int r = wn + ni*16 + ql;                                                 \
        bfr[ni] = *(const bf16x8*)((char*)(buf) + r*128 + ((64 + lg*16) ^ ((r & 7) << 4))); \
      }                                                                          \
      __builtin_amdgcn_s_setprio(1);                                             \
      _Pragma("unroll")                                                          \
      for (int mi = 0; mi < 4; mi++)                                             \
        _Pragma("unroll")                                                        \
        for (int ni = 0; ni < 4; ni++)                                           \
          acc[mi][ni] = SWAP ? mfma16(bfr[ni], af[mi], acc[mi][ni])              \
                             : mfma16(af[mi], bfr[ni], acc[mi][ni]);             \
      __builtin_amdgcn_s_setprio(0);                                             \
    }

  char* b0 = (char*)S;
  char* b1 = (char*)S + 16384;
  char* b2 = (char*)S + 32768;

  STAGE_G(b0, 0);
  STAGE_G(b1, 32);

  #pragma unroll 3
  for (int t = 0; t < 30; t++){
    asm volatile("s_waitcnt vmcnt(4)" ::: "memory");   // stage(t) done, stage(t+1) in flight
    __builtin_amdgcn_s_barrier();                      // everyone's stage(t) done
    STAGE_G(b2, (t+2)*32);                             // depth-2 prefetch
    COMPUTE_T(b0);
    char* tmp = b0; b0 = b1; b1 = b2; b2 = tmp;        // rotate (static after unroll 3)
  }
  // t = 30: nothing left to stage; stage(31) still in flight
  asm volatile("s_waitcnt vmcnt(4)" ::: "memory");
  __builtin_amdgcn_s_barrier();
  COMPUTE_T(b0);
  { char* tmp = b0; b0 = b1; b1 = b2; b2 = tmp; }
  // t = 31: only stage(31)'s 4 loads outstanding -> full drain
  asm volatile("s_waitcnt vmcnt(0)" ::: "memory");
  __builtin_amdgcn_s_barrier();
  COMPUTE_T(b0);

  #undef STAGE_G
  #undef COMPUTE_T
}

// QKV GEMM. z=0/1: fused RoPE (trig table), row-major out. z=2: V written
// TRANSPOSED as V^T[b][h*64+d][s]  (feature-major, so attn can gl16-stage it).
__global__ __launch_bounds__(256) void k_gemm_qkv(const u16* __restrict__ xb, const u16* __restrict__ Wb,
                                                  u16* __restrict__ Qb, u16* __restrict__ Kb,
                                                  u16* __restrict__ Vt_g, const int* __restrict__ pos,
                                                  const float* __restrict__ tab){
  __shared__ __align__(16) u16 S[3*8192];
  const int z = blockIdx.z;
  const u16* Bw = Wb + ((size_t)z << 20);
  f32x4 acc[4][4] = {};
  gemm_core<true>(xb, Bw, S, acc);
  const int lane = threadIdx.x & 63, wid = threadIdx.x >> 6;
  const int m0 = blockIdx.y*128 + (wid >> 1)*64, n0 = blockIdx.x*128 + (wid & 1)*64;
  const int ql = lane & 15, lg = lane >> 4;

  if (z == 2){
    #pragma unroll
    for (int mi = 0; mi < 4; mi++){
      const int mrow = m0 + mi*16 + ql;
      const int bq = mrow >> 11, sq = mrow & (SS-1);
      u16* vt = Vt_g + ((size_t)bq*NH*DK)*SS + sq;
      #pragma unroll
      for (int ni = 0; ni < 4; ni++){
        const int nb = n0 + ni*16 + lg*4;
        #pragma unroll
        for (int r = 0; r < 4; r++)
          vt[(size_t)(nb + r)*SS] = f2bf(acc[mi][ni][r]);
      }
    }
    return;
  }

  u16* C = (z == 0) ? Qb : Kb;
  const float4* tab4 = (const float4*)tab;     // [p][j/2] = {cos j, sin j, cos j+1, sin j+1}
  #pragma unroll
  for (int mi = 0; mi < 4; mi++){
    const int mrow = m0 + mi*16 + ql;
    const int p = pos[mrow & (SS-1)];
    #pragma unroll
    for (int ni = 0; ni < 4; ni++){
      const int nb = n0 + ni*16 + lg*4;        // 4 consecutive n, multiple of 4
      float o0 = acc[mi][ni][0], o1 = acc[mi][ni][1];
      float o2 = acc[mi][ni][2], o3 = acc[mi][ni][3];
      int j0 = (nb >> 1) & 31;                 // even pair index within head
      float4 cs = tab4[p*16 + (j0 >> 1)];
      float t0 = o0*cs.x - o1*cs.y, t1 = o0*cs.y + o1*cs.x;
      o0 = t0; o1 = t1;
      t0 = o2*cs.z - o3*cs.w; t1 = o2*cs.w + o3*cs.z;
      o2 = t0; o3 = t1;
      uint2 w; w.x = cvtpk(o0, o1); w.y = cvtpk(o2, o3);
      *(uint2*)(C + (size_t)mrow*DM + nb) = w;
    }
  }
}

__global__ __launch_bounds__(256) void k_gemm_out(const u16* __restrict__ AO, const u16* __restrict__ Wo,
                                                  float* __restrict__ Co){
  __shared__ __align__(16) u16 S[3*8192];
  f32x4 acc[4][4] = {};
  gemm_core<false>(AO, Wo, S, acc);
  const int lane = threadIdx.x & 63, wid = threadIdx.x >> 6;
  const int m0 = blockIdx.y*128 + (wid >> 1)*64, n0 = blockIdx.x*128 + (wid & 1)*64;
  #pragma unroll
  for (int mi = 0; mi < 4; mi++)
    #pragma unroll
    for (int ni = 0; ni < 4; ni++)
      #pragma unroll
      for (int r = 0; r < 4; r++){
        int m = m0 + mi*16 + (lane >> 4)*4 + r;
        int n = n0 + ni*16 + (lane & 15);
        Co[(size_t)m*DM + n] = acc[mi][ni][r];
      }
}

// ---------------- flash attention, causal, 8-wave QBLK=128 (R8, verified) ----------
__global__ __launch_bounds__(512) void k_attn(const u16* __restrict__ Q, const u16* __restrict__ K,
                                              const u16* __restrict__ Vt_g, u16* __restrict__ AO){
  __shared__ __align__(16) u16 Ks[2][64*64];
  __shared__ __align__(16) u16 Vt[2][64*64];
  __shared__ __align__(16) u16 Ps[8][16*64];
  const int tid = threadIdx.x, lane = tid & 63, wid = tid >> 6;
  const int b = blockIdx.z, h = blockIdx.y;
  const int qb = b ? (15 - (int)blockIdx.x) : (int)blockIdx.x;   // balanced pairing
  const int qw = qb*128 + wid*16;
  const size_t base = ((size_t)b*SS)*DM + (size_t)h*DK;
  const size_t vtb  = ((size_t)b*NH + h)*DK*SS;                  // V^T base
  const int ql = lane & 15, lg = lane >> 4;
  const int NT = 2*qb + 2;

  const u16* qptr = Q + base + (size_t)(qw + ql)*DM + lg*8;
  bf16x8 qf0 = *(const bf16x8*)(qptr);
  bf16x8 qf1 = *(const bf16x8*)(qptr + 32);

  f32x4 oacc[4] = {};
  float m = -3e38f, lsum = 0.f;
  const float SC = 0.18033688011112042f;        // (1/sqrt(64)) * log2(e)
  const float THR = 8.0f / SC;

  const int srow = tid >> 3;
  const int sin = ((tid & 7) * 16) ^ ((srow & 7) << 4);   // pre-swizzled byte col

  gl16(K    + base + (size_t)srow*DM + (sin >> 1), (char*)Ks[0] + tid*16);
  gl16(Vt_g + vtb  + (size_t)srow*SS + (sin >> 1), (char*)Vt[0] + tid*16);
  __syncthreads();

  int cur = 0;
  for (int kt = 0; kt < NT; kt++){
    const int kv0 = kt*64;
    const bool more = (kt < NT-1);
    if (more){
      const int kn0 = kv0 + 64;
      gl16(K    + base + (size_t)(kn0+srow)*DM + (sin >> 1), (char*)Ks[cur^1] + tid*16);
      gl16(Vt_g + vtb  + (size_t)srow*SS + kn0 + (sin >> 1), (char*)Vt[cur^1] + tid*16);
    }

    const bool active = (kv0 <= qw + 15);
    if (active){
      f32x4 sf[4] = {};
      __builtin_amdgcn_s_setprio(1);
      #pragma unroll
      for (int kk = 0; kk < 2; kk++){
        const int co = kk*64 + lg*16;
        #pragma unroll
        for (int f = 0; f < 4; f++){
          int kvr = f*16 + ql;
          bf16x8 kf = *(const bf16x8*)((const char*)Ks[cur] + ((kvr*128 + co) ^ ((kvr & 7) << 4)));
          sf[f] = mfma16(kf, kk ? qf1 : qf0, sf[f]);
        }
      }
      __builtin_amdgcn_s_setprio(0);

      if (kv0 + 63 > qw){
        const int qa = qw + ql;
        #pragma unroll
        for (int f = 0; f < 4; f++)
          #pragma unroll
          for (int r = 0; r < 4; r++){
            int kva = kv0 + f*16 + lg*4 + r;
            sf[f][r] = (kva <= qa) ? sf[f][r] : -3e38f;
          }
      }

      float mx01 = fmaxf(fmaxf(sf[0][0], sf[0][1]), fmaxf(sf[0][2], sf[0][3]));
      float mx23 = fmaxf(fmaxf(sf[1][0], sf[1][1]), fmaxf(sf[1][2], sf[1][3]));
      float mx45 = fmaxf(fmaxf(sf[2][0], sf[2][1]), fmaxf(sf[2][2], sf[2][3]));
      float mx67 = fmaxf(fmaxf(sf[3][0], sf[3][1]), fmaxf(sf[3][2], sf[3][3]));
      float mx = fmaxf(fmaxf(mx01, mx23), fmaxf(mx45, mx67));

      if (!__all(mx <= m + THR)){               // defer-max
        mx = fmaxf(mx, __shfl_xor(mx, 16));
        mx = fmaxf(mx, __shfl_xor(mx, 32));
        const float mn = fmaxf(m, mx);
        const float alpha = exp2f((m - mn)*SC);
        #pragma unroll
        for (int ni = 0; ni < 4; ni++) oacc[ni] *= alpha;
        lsum *= alpha;
        m = mn;
      }

      const float nms = -m*SC;
      float p[4][4];
      float psum = 0.f;
      #pragma unroll
      for (int f = 0; f < 4; f++)
        #pragma unroll
        for (int r = 0; r < 4; r++){
          p[f][r] = exp2f(fmaf(sf[f][r], SC, nms));
          psum += p[f][r];
        }
      lsum += psum;

      #pragma unroll
      for (int f = 0; f < 4; f++)
        #pragma unroll
        for (int r = 0; r < 4; r += 2){
          int kv = f*16 + lg*4 + r;
          int byteoff = (ql*128 + kv*2) ^ ((ql & 7) << 4);
          *(u32*)((char*)Ps[wid] + byteoff) = cvtpk(p[f][r], p[f][r+1]);
        }

      __builtin_amdgcn_s_setprio(1);
      #pragma unroll
      for (int kk = 0; kk < 2; kk++){
        bf16x8 pf = *(const bf16x8*)((const char*)Ps[wid] +
                      ((ql*128 + kk*64 + lg*16) ^ ((ql & 7) << 4)));
        #pragma unroll
        for (int ni = 0; ni < 4; ni++){
          int d = ni*16 + ql;
          bf16x8 vf = *(const bf16x8*)((const char*)Vt[cur] +
                        ((d*128 + kk*64 + lg*16) ^ ((d & 7) << 4)));
          oacc[ni] = mfma16(vf, pf, oacc[ni]);
        }
      }
      __builtin_amdgcn_s_setprio(0);
    }

    __syncthreads();
    cur ^= 1;
  }

  lsum += __shfl_xor(lsum, 16);
  lsum += __shfl_xor(lsum, 32);
  const float rl = 1.0f / lsum;
  #pragma unroll
  for (int ni = 0; ni < 4; ni++)
    #pragma unroll
    for (int r = 0; r < 4; r += 2){
      int d = ni*16 + lg*4 + r;
      int byteoff = (ql*128 + d*2) ^ ((ql & 7) << 4);
      *(u32*)((char*)Ps[wid] + byteoff) = cvtpk(oacc[ni][r]*rl, oacc[ni][r+1]*rl);
    }
  #pragma unroll
  for (int pass = 0; pass < 2; pass++){
    int qr = pass*8 + (lane >> 3);
    int d0 = (lane & 7)*8;
    bf16x8 row = *(const bf16x8*)((const char*)Ps[wid] + ((qr*128 + d0*2) ^ ((qr & 7) << 4)));
    *(bf16x8*)(AO + base + (size_t)(qw + qr)*DM + d0) = row;
  }
}

// ---------------- launch ----------------
extern "C" void kernel_launch(void* const* d_in, const int* in_sizes, int n_in,
                              void* d_out, int out_size, void* d_ws, size_t ws_size,
                              hipStream_t stream){
  const float* x   = (const float*)d_in[0];
  const float* Wq  = (const float*)d_in[1];
  const float* Wk  = (const float*)d_in[2];
  const float* Wv  = (const float*)d_in[3];
  const float* Wo  = (const float*)d_in[4];
  const int*   pos = (const int*)d_in[5];
  float* out = (float*)d_out;

  const size_t NEED = ((size_t)41 << 20);   // 40 MiB buffers + 512 KiB trig table
  if (ws_size < NEED){
    hipMemsetAsync(d_out, 0x7f, (size_t)out_size * sizeof(float), stream);
    return;
  }

  char* ws = (char*)d_ws;
  u16* xb   = (u16*)(ws);
  u16* Wb   = (u16*)(ws + ((size_t)8  << 20));
  u16* Qb   = (u16*)(ws + ((size_t)16 << 20));
  u16* Kb   = (u16*)(ws + ((size_t)24 << 20));
  u16* Vt   = (u16*)(ws + ((size_t)32 << 20));   // V^T [b][h*64+d][s]
  float* tab = (float*)(ws + ((size_t)40 << 20));
  u16* AO = xb;

  k_cast<<<8448, 256, 0, stream>>>(x, Wq, Wk, Wv, Wo, xb, Wb, tab);
  k_gemm_qkv<<<dim3(8, 32, 3), 256, 0, stream>>>(xb, Wb, Qb, Kb, Vt, pos, tab);
  k_attn<<<dim3(16, 16, 2), 512, 0, stream>>>(Qb, Kb, Vt, AO);
  k_gemm_out<<<dim3(8, 32), 256, 0, stream>>>(AO, Wb + ((size_t)3 << 20), out);
}

// Round 11
// 122.298 us; speedup vs baseline: 1.4186x; 1.0104x over previous
//
#include <hip/hip_runtime.h>

#define DM 1024
#define NH 16
#define DK 64
#define BB 2
#define SS 2048

typedef unsigned short u16;
typedef unsigned int   u32;
typedef __bf16 bf16x8 __attribute__((ext_vector_type(8)));
typedef float  f32x4  __attribute__((ext_vector_type(4)));

__device__ __forceinline__ u16 f2bf(float f){
  u32 u = __float_as_uint(f);
  u32 r = (u + 0x7FFFu + ((u >> 16) & 1u)) >> 16;   // RNE
  return (u16)r;
}
__device__ __forceinline__ float bf2f(u16 v){ return __uint_as_float(((u32)v) << 16); }

// packed bf16 convert: low16 = bf16(lo), high16 = bf16(hi), RNE
__device__ __forceinline__ u32 cvtpk(float lo, float hi){
  u32 r;
  asm volatile("v_cvt_pk_bf16_f32 %0, %1, %2" : "=v"(r) : "v"(lo), "v"(hi));
  return r;
}

__device__ __forceinline__ void gl16(const void* g, void* l){
  __builtin_amdgcn_global_load_lds((const __attribute__((address_space(1))) u32*)g,
                                   (__attribute__((address_space(3))) u32*)l, 16, 0, 0);
}
__device__ __forceinline__ f32x4 mfma16(bf16x8 a, bf16x8 b, f32x4 c){
  return __builtin_amdgcn_mfma_f32_16x16x32_bf16(a, b, c, 0, 0, 0);
}

// ------- merged cast (x + 4 weights) + RoPE trig-table fill (tail blocks) -------
__global__ void k_cast(const float* __restrict__ x,  const float* __restrict__ wq,
                       const float* __restrict__ wk, const float* __restrict__ wv,
                       const float* __restrict__ wo, u16* __restrict__ xb,
                       u16* __restrict__ wb, float* __restrict__ tab){
  if (blockIdx.x >= 8192){
    int e = (blockIdx.x - 8192)*256 + threadIdx.x;   // [0, 65536)
    int p = e >> 5, j = e & 31;
    float s, c;
    sincosf((float)p * exp2f(-0.4152410118609203f * (float)j), &s, &c);
    float2 v; v.x = c; v.y = s;
    *(float2*)(tab + e*2) = v;
    return;
  }
  int e = blockIdx.x*1024 + threadIdx.x*4;
  int r = e >> 20;
  const float* s; u16* d; int local;
  if (r < 4){ s = x; d = xb; local = e; }
  else {
    const float* ws[4] = {wq, wk, wv, wo};
    int w = r - 4;
    local = e & 0xFFFFF;
    s = ws[w]; d = wb + ((size_t)w << 20);
  }
  float4 v = *(const float4*)(s + local);
  uint2 t; t.x = cvtpk(v.x, v.y); t.y = cvtpk(v.z, v.w);
  *(uint2*)(d + local) = t;
}

// ---------------- GEMM core R10 (verified): BK=32, triple-buffer, counted vmcnt ----
template<bool SWAP>
__device__ __forceinline__ void gemm_core(const u16* __restrict__ A, const u16* __restrict__ Bw,
                                          u16* S, f32x4 (&acc)[4][4]){
  const int tid = threadIdx.x, lane = tid & 63, wid = tid >> 6;
  const int m0 = blockIdx.y * 128, n0 = blockIdx.x * 128;
  const int wm = (wid >> 1) * 64, wn = (wid & 1) * 64;
  const int ql = lane & 15, lg = lane >> 4;

  #define STAGE_G(buf, k0)                                                       \
    _Pragma("unroll")                                                            \
    for (int i = 0; i < 4; i++){                                                 \
      int L = i*4096 + tid*16;                                                   \
      int r_ = L >> 7;                                                           \
      int orig = ((L >> 4) & 7) ^ (r_ & 7);                                      \
      const u16* src = (orig < 4)                                                \
          ? (A  + (size_t)(m0 + r_)*DM + (k0) + orig*8)                          \
          : (Bw + (size_t)(n0 + r_)*DM + (k0) + (orig - 4)*8);                   \
      gl16(src, (char*)(buf) + L);                                               \
    }

  #define COMPUTE_T(buf)                                                         \
    {                                                                            \
      bf16x8 af[4], bfr[4];                                                      \
      _Pragma("unroll")                                                          \
      for (int mi = 0; mi < 4; mi++){                                            \
        int r = wm + mi*16 + ql;                                                 \
        af[mi] = *(const bf16x8*)((char*)(buf) + r*128 + ((lg*16) ^ ((r & 7) << 4))); \
      }                                                                          \
      _Pragma("unroll")                                                          \
      for (int ni = 0; ni < 4; ni++){                                            \
        int r = wn + ni*16 + ql;                                                 \
        bfr[ni] = *(const bf16x8*)((char*)(buf) + r*128 + ((64 + lg*16) ^ ((r & 7) << 4))); \
      }                                                                          \
      __builtin_amdgcn_s_setprio(1);                                             \
      _Pragma("unroll")                                                          \
      for (int mi = 0; mi < 4; mi++)                                             \
        _Pragma("unroll")                                                        \
        for (int ni = 0; ni < 4; ni++)                                           \
          acc[mi][ni] = SWAP ? mfma16(bfr[ni], af[mi], acc[mi][ni])              \
                             : mfma16(af[mi], bfr[ni], acc[mi][ni]);             \
      __builtin_amdgcn_s_setprio(0);                                             \
    }

  char* b0 = (char*)S;
  char* b1 = (char*)S + 16384;
  char* b2 = (char*)S + 32768;

  STAGE_G(b0, 0);
  STAGE_G(b1, 32);

  #pragma unroll 3
  for (int t = 0; t < 30; t++){
    asm volatile("s_waitcnt vmcnt(4)" ::: "memory");   // stage(t) done, stage(t+1) in flight
    __builtin_amdgcn_s_barrier();                      // everyone's stage(t) done
    STAGE_G(b2, (t+2)*32);                             // depth-2 prefetch
    COMPUTE_T(b0);
    char* tmp = b0; b0 = b1; b1 = b2; b2 = tmp;        // rotate (static after unroll 3)
  }
  asm volatile("s_waitcnt vmcnt(4)" ::: "memory");
  __builtin_amdgcn_s_barrier();
  COMPUTE_T(b0);
  { char* tmp = b0; b0 = b1; b1 = b2; b2 = tmp; }
  asm volatile("s_waitcnt vmcnt(0)" ::: "memory");
  __builtin_amdgcn_s_barrier();
  COMPUTE_T(b0);

  #undef STAGE_G
  #undef COMPUTE_T
}

// QKV GEMM. z=0/1: fused RoPE (trig table), row-major out. z=2: V written
// TRANSPOSED as V^T[b][h*64+d][s]  (feature-major, so attn can gl16-stage it).
__global__ __launch_bounds__(256) void k_gemm_qkv(const u16* __restrict__ xb, const u16* __restrict__ Wb,
                                                  u16* __restrict__ Qb, u16* __restrict__ Kb,
                                                  u16* __restrict__ Vt_g, const int* __restrict__ pos,
                                                  const float* __restrict__ tab){
  __shared__ __align__(16) u16 S[3*8192];
  const int z = blockIdx.z;
  const u16* Bw = Wb + ((size_t)z << 20);
  f32x4 acc[4][4] = {};
  gemm_core<true>(xb, Bw, S, acc);
  const int lane = threadIdx.x & 63, wid = threadIdx.x >> 6;
  const int m0 = blockIdx.y*128 + (wid >> 1)*64, n0 = blockIdx.x*128 + (wid & 1)*64;
  const int ql = lane & 15, lg = lane >> 4;

  if (z == 2){
    #pragma unroll
    for (int mi = 0; mi < 4; mi++){
      const int mrow = m0 + mi*16 + ql;
      const int bq = mrow >> 11, sq = mrow & (SS-1);
      u16* vt = Vt_g + ((size_t)bq*NH*DK)*SS + sq;
      #pragma unroll
      for (int ni = 0; ni < 4; ni++){
        const int nb = n0 + ni*16 + lg*4;
        #pragma unroll
        for (int r = 0; r < 4; r++)
          vt[(size_t)(nb + r)*SS] = f2bf(acc[mi][ni][r]);
      }
    }
    return;
  }

  u16* C = (z == 0) ? Qb : Kb;
  const float4* tab4 = (const float4*)tab;     // [p][j/2] = {cos j, sin j, cos j+1, sin j+1}
  #pragma unroll
  for (int mi = 0; mi < 4; mi++){
    const int mrow = m0 + mi*16 + ql;
    const int p = pos[mrow & (SS-1)];
    #pragma unroll
    for (int ni = 0; ni < 4; ni++){
      const int nb = n0 + ni*16 + lg*4;        // 4 consecutive n, multiple of 4
      float o0 = acc[mi][ni][0], o1 = acc[mi][ni][1];
      float o2 = acc[mi][ni][2], o3 = acc[mi][ni][3];
      int j0 = (nb >> 1) & 31;                 // even pair index within head
      float4 cs = tab4[p*16 + (j0 >> 1)];
      float t0 = o0*cs.x - o1*cs.y, t1 = o0*cs.y + o1*cs.x;
      o0 = t0; o1 = t1;
      t0 = o2*cs.z - o3*cs.w; t1 = o2*cs.w + o3*cs.z;
      o2 = t0; o3 = t1;
      uint2 w; w.x = cvtpk(o0, o1); w.y = cvtpk(o2, o3);
      *(uint2*)(C + (size_t)mrow*DM + nb) = w;
    }
  }
}

__global__ __launch_bounds__(256) void k_gemm_out(const u16* __restrict__ AO, const u16* __restrict__ Wo,
                                                  float* __restrict__ Co){
  __shared__ __align__(16) u16 S[3*8192];
  f32x4 acc[4][4] = {};
  gemm_core<false>(AO, Wo, S, acc);
  const int lane = threadIdx.x & 63, wid = threadIdx.x >> 6;
  const int m0 = blockIdx.y*128 + (wid >> 1)*64, n0 = blockIdx.x*128 + (wid & 1)*64;
  #pragma unroll
  for (int mi = 0; mi < 4; mi++)
    #pragma unroll
    for (int ni = 0; ni < 4; ni++)
      #pragma unroll
      for (int r = 0; r < 4; r++){
        int m = m0 + mi*16 + (lane >> 4)*4 + r;
        int n = n0 + ni*16 + (lane & 15);
        Co[(size_t)m*DM + n] = acc[mi][ni][r];
      }
}

// ---------------- flash attention, causal, 8-wave QBLK=128 ----------------
// R11: T4 port — triple-buffered K/V LDS, depth-2 prefetch, raw s_barrier with
// counted s_waitcnt vmcnt(2) (stage(t+1) done, stage(t+2)'s 2 loads in flight;
// never drains to 0 in the loop). Same lever that took the GEMM 62 -> ~40 us.
__global__ __launch_bounds__(512) void k_attn(const u16* __restrict__ Q, const u16* __restrict__ K,
                                              const u16* __restrict__ Vt_g, u16* __restrict__ AO){
  __shared__ __align__(16) u16 Ks[3][64*64];
  __shared__ __align__(16) u16 Vt[3][64*64];
  __shared__ __align__(16) u16 Ps[8][16*64];
  const int tid = threadIdx.x, lane = tid & 63, wid = tid >> 6;
  const int b = blockIdx.z, h = blockIdx.y;
  const int qb = b ? (15 - (int)blockIdx.x) : (int)blockIdx.x;   // balanced pairing
  const int qw = qb*128 + wid*16;
  const size_t base = ((size_t)b*SS)*DM + (size_t)h*DK;
  const size_t vtb  = ((size_t)b*NH + h)*DK*SS;                  // V^T base
  const int ql = lane & 15, lg = lane >> 4;
  const int NT = 2*qb + 2;

  const u16* qptr = Q + base + (size_t)(qw + ql)*DM + lg*8;
  bf16x8 qf0 = *(const bf16x8*)(qptr);
  bf16x8 qf1 = *(const bf16x8*)(qptr + 32);

  f32x4 oacc[4] = {};
  float m = -3e38f, lsum = 0.f;
  const float SC = 0.18033688011112042f;        // (1/sqrt(64)) * log2(e)
  const float THR = 8.0f / SC;

  const int srow = tid >> 3;
  const int sin = ((tid & 7) * 16) ^ ((srow & 7) << 4);   // pre-swizzled byte col

  #define STAGE_A(bi, t)                                                          \
    {                                                                             \
      const int kn0_ = (t)*64;                                                    \
      gl16(K    + base + (size_t)(kn0_ + srow)*DM + (sin >> 1), (char*)Ks[bi] + tid*16); \
      gl16(Vt_g + vtb  + (size_t)srow*SS + kn0_ + (sin >> 1), (char*)Vt[bi] + tid*16);   \
    }

  STAGE_A(0, 0);
  STAGE_A(1, 1);                      // NT >= 2 always
  asm volatile("s_waitcnt vmcnt(2)" ::: "memory");   // stage(0) (and Q) done
  __builtin_amdgcn_s_barrier();

  int c0 = 0, c1 = 1, c2 = 2;
  for (int kt = 0; kt < NT; kt++){
    const int kv0 = kt*64;
    const bool have2 = (kt + 2 < NT);
    if (have2) STAGE_A(c2, kt + 2);   // depth-2 prefetch

    const bool active = (kv0 <= qw + 15);
    if (active){
      f32x4 sf[4] = {};
      __builtin_amdgcn_s_setprio(1);
      #pragma unroll
      for (int kk = 0; kk < 2; kk++){
        const int co = kk*64 + lg*16;
        #pragma unroll
        for (int f = 0; f < 4; f++){
          int kvr = f*16 + ql;
          bf16x8 kf = *(const bf16x8*)((const char*)Ks[c0] + ((kvr*128 + co) ^ ((kvr & 7) << 4)));
          sf[f] = mfma16(kf, kk ? qf1 : qf0, sf[f]);
        }
      }
      __builtin_amdgcn_s_setprio(0);

      if (kv0 + 63 > qw){
        const int qa = qw + ql;
        #pragma unroll
        for (int f = 0; f < 4; f++)
          #pragma unroll
          for (int r = 0; r < 4; r++){
            int kva = kv0 + f*16 + lg*4 + r;
            sf[f][r] = (kva <= qa) ? sf[f][r] : -3e38f;
          }
      }

      float mx01 = fmaxf(fmaxf(sf[0][0], sf[0][1]), fmaxf(sf[0][2], sf[0][3]));
      float mx23 = fmaxf(fmaxf(sf[1][0], sf[1][1]), fmaxf(sf[1][2], sf[1][3]));
      float mx45 = fmaxf(fmaxf(sf[2][0], sf[2][1]), fmaxf(sf[2][2], sf[2][3]));
      float mx67 = fmaxf(fmaxf(sf[3][0], sf[3][1]), fmaxf(sf[3][2], sf[3][3]));
      float mx = fmaxf(fmaxf(mx01, mx23), fmaxf(mx45, mx67));

      if (!__all(mx <= m + THR)){               // defer-max
        mx = fmaxf(mx, __shfl_xor(mx, 16));
        mx = fmaxf(mx, __shfl_xor(mx, 32));
        const float mn = fmaxf(m, mx);
        const float alpha = exp2f((m - mn)*SC);
        #pragma unroll
        for (int ni = 0; ni < 4; ni++) oacc[ni] *= alpha;
        lsum *= alpha;
        m = mn;
      }

      const float nms = -m*SC;
      float p[4][4];
      float psum = 0.f;
      #pragma unroll
      for (int f = 0; f < 4; f++)
        #pragma unroll
        for (int r = 0; r < 4; r++){
          p[f][r] = exp2f(fmaf(sf[f][r], SC, nms));
          psum += p[f][r];
        }
      lsum += psum;

      #pragma unroll
      for (int f = 0; f < 4; f++)
        #pragma unroll
        for (int r = 0; r < 4; r += 2){
          int kv = f*16 + lg*4 + r;
          int byteoff = (ql*128 + kv*2) ^ ((ql & 7) << 4);
          *(u32*)((char*)Ps[wid] + byteoff) = cvtpk(p[f][r], p[f][r+1]);
        }

      __builtin_amdgcn_s_setprio(1);
      #pragma unroll
      for (int kk = 0; kk < 2; kk++){
        bf16x8 pf = *(const bf16x8*)((const char*)Ps[wid] +
                      ((ql*128 + kk*64 + lg*16) ^ ((ql & 7) << 4)));
        #pragma unroll
        for (int ni = 0; ni < 4; ni++){
          int d = ni*16 + ql;
          bf16x8 vf = *(const bf16x8*)((const char*)Vt[c0] +
                        ((d*128 + kk*64 + lg*16) ^ ((d & 7) << 4)));
          oacc[ni] = mfma16(vf, pf, oacc[ni]);
        }
      }
      __builtin_amdgcn_s_setprio(0);
    }

    if (kt + 1 < NT){
      if (have2) asm volatile("s_waitcnt vmcnt(2)" ::: "memory");  // stage(t+1) done
      else       asm volatile("s_waitcnt vmcnt(0)" ::: "memory");  // final drain
      __builtin_amdgcn_s_barrier();
    }
    int tmp = c0; c0 = c1; c1 = c2; c2 = tmp;
  }
  #undef STAGE_A

  lsum += __shfl_xor(lsum, 16);
  lsum += __shfl_xor(lsum, 32);
  const float rl = 1.0f / lsum;
  #pragma unroll
  for (int ni = 0; ni < 4; ni++)
    #pragma unroll
    for (int r = 0; r < 4; r += 2){
      int d = ni*16 + lg*4 + r;
      int byteoff = (ql*128 + d*2) ^ ((ql & 7) << 4);
      *(u32*)((char*)Ps[wid] + byteoff) = cvtpk(oacc[ni][r]*rl, oacc[ni][r+1]*rl);
    }
  #pragma unroll
  for (int pass = 0; pass < 2; pass++){
    int qr = pass*8 + (lane >> 3);
    int d0 = (lane & 7)*8;
    bf16x8 row = *(const bf16x8*)((const char*)Ps[wid] + ((qr*128 + d0*2) ^ ((qr & 7) << 4)));
    *(bf16x8*)(AO + base + (size_t)(qw + qr)*DM + d0) = row;
  }
}

// ---------------- launch ----------------
extern "C" void kernel_launch(void* const* d_in, const int* in_sizes, int n_in,
                              void* d_out, int out_size, void* d_ws, size_t ws_size,
                              hipStream_t stream){
  const float* x   = (const float*)d_in[0];
  const float* Wq  = (const float*)d_in[1];
  const float* Wk  = (const float*)d_in[2];
  const float* Wv  = (const float*)d_in[3];
  const float* Wo  = (const float*)d_in[4];
  const int*   pos = (const int*)d_in[5];
  float* out = (float*)d_out;

  const size_t NEED = ((size_t)41 << 20);   // 40 MiB buffers + 512 KiB trig table
  if (ws_size < NEED){
    hipMemsetAsync(d_out, 0x7f, (size_t)out_size * sizeof(float), stream);
    return;
  }

  char* ws = (char*)d_ws;
  u16* xb   = (u16*)(ws);
  u16* Wb   = (u16*)(ws + ((size_t)8  << 20));
  u16* Qb   = (u16*)(ws + ((size_t)16 << 20));
  u16* Kb   = (u16*)(ws + ((size_t)24 << 20));
  u16* Vt   = (u16*)(ws + ((size_t)32 << 20));   // V^T [b][h*64+d][s]
  float* tab = (float*)(ws + ((size_t)40 << 20));
  u16* AO = xb;

  k_cast<<<8448, 256, 0, stream>>>(x, Wq, Wk, Wv, Wo, xb, Wb, tab);
  k_gemm_qkv<<<dim3(8, 32, 3), 256, 0, stream>>>(xb, Wb, Qb, Kb, Vt, pos, tab);
  k_attn<<<dim3(16, 16, 2), 512, 0, stream>>>(Qb, Kb, Vt, AO);
  k_gemm_out<<<dim3(8, 32), 256, 0, stream>>>(AO, Wb + ((size_t)3 << 20), out);
}